// Round 1
// baseline (707.903 us; speedup 1.0000x reference)
//
#include <hip/hip_runtime.h>

// DecoderAttention: B=8, T=1024, N=512, L=4096, D=512, F=64, BR=8
#define B_ 8
#define T_ 1024
#define N_ 512
#define L_ 4096
#define D_ 512
#define F_ 64

// ---------------------------------------------------------------------------
// Projection kernel: X [R,512] -> K = X@Wk + bk  (+ V, + agg logits, + fused
// per-node-group interp sums G for the leaf pass).
// 32 rows/block staged in LDS (64KB); wave w owns rows w*8..w*8+7, lane = f.
// ---------------------------------------------------------------------------
template<int HAS_V, int HAS_AGG>
__global__ __launch_bounds__(256)
void proj_kernel(const float* __restrict__ X,
                 const float* __restrict__ Wk, const float* __restrict__ bk, float* __restrict__ outK,
                 const float* __restrict__ Wv, const float* __restrict__ bv, float* __restrict__ outV,
                 const float* __restrict__ Wagg, const float* __restrict__ bagg, float* __restrict__ outAgg,
                 const float* __restrict__ root, const float* __restrict__ node_v, float* __restrict__ G_t)
{
    __shared__ float Xs[32 * D_];   // 64 KB
    const int tid = threadIdx.x;
    const int r0  = blockIdx.x * 32;

    const float4* src = (const float4*)(X + (size_t)r0 * D_);
    float4* dst = (float4*)Xs;
    #pragma unroll
    for (int i = 0; i < 16; ++i) dst[tid + i * 256] = src[tid + i * 256];
    __syncthreads();

    const int w = tid >> 6;
    const int f = tid & 63;
    const float* xbase = Xs + w * 8 * D_;

    float accK[8] = {0,0,0,0,0,0,0,0};
    float accV[8] = {0,0,0,0,0,0,0,0};

    for (int d = 0; d < D_; d += 4) {
        const float k0 = Wk[(d+0)*F_ + f];
        const float k1 = Wk[(d+1)*F_ + f];
        const float k2 = Wk[(d+2)*F_ + f];
        const float k3 = Wk[(d+3)*F_ + f];
        float v0 = 0.f, v1 = 0.f, v2 = 0.f, v3 = 0.f;
        if constexpr (HAS_V) {
            v0 = Wv[(d+0)*F_ + f]; v1 = Wv[(d+1)*F_ + f];
            v2 = Wv[(d+2)*F_ + f]; v3 = Wv[(d+3)*F_ + f];
        }
        #pragma unroll
        for (int r = 0; r < 8; ++r) {
            const float4 x = *(const float4*)(xbase + r * D_ + d);  // broadcast read
            accK[r] = fmaf(x.x,k0, fmaf(x.y,k1, fmaf(x.z,k2, fmaf(x.w,k3, accK[r]))));
            if constexpr (HAS_V)
                accV[r] = fmaf(x.x,v0, fmaf(x.y,v1, fmaf(x.z,v2, fmaf(x.w,v3, accV[r]))));
        }
    }

    const float bkf = bk[f];
    float bvf = 0.f;
    if constexpr (HAS_V) bvf = bv[f];
    #pragma unroll
    for (int r = 0; r < 8; ++r) {
        const int row = r0 + w*8 + r;
        outK[(size_t)row * F_ + f] = accK[r] + bkf;
        if constexpr (HAS_V) outV[(size_t)row * F_ + f] = accV[r] + bvf;
    }

    if constexpr (HAS_AGG) {
        // agg logit per row: lane f covers d = f*8..f*8+7, then wave reduce
        const float4 wa0 = *(const float4*)(Wagg + f*8);
        const float4 wa1 = *(const float4*)(Wagg + f*8 + 4);
        const float bagg0 = bagg[0];
        #pragma unroll
        for (int r = 0; r < 8; ++r) {
            const float4 x0 = *(const float4*)(xbase + r*D_ + f*8);
            const float4 x1 = *(const float4*)(xbase + r*D_ + f*8 + 4);
            float p = x0.x*wa0.x + x0.y*wa0.y + x0.z*wa0.z + x0.w*wa0.w
                    + x1.x*wa1.x + x1.y*wa1.y + x1.z*wa1.z + x1.w*wa1.w;
            #pragma unroll
            for (int off = 1; off < 64; off <<= 1) p += __shfl_xor(p, off);
            if (f == 0) outAgg[r0 + w*8 + r] = p + bagg0;
        }
        // fused node-group interp sum: wave w's 8 rows == one node group
        const int b  = r0 >> 12;          // 4096 leaf rows per batch
        const int l0 = r0 & (L_ - 1);
        const int n  = (l0 >> 3) + w;
        const float rootf = root[b*F_ + f];
        const float nvf   = node_v[((size_t)(b*N_ + n))*F_ + f];
        float s = 0.f;
        #pragma unroll
        for (int r = 0; r < 8; ++r) s += accV[r] + bvf;
        s += 8.f * (rootf + nvf);
        G_t[((size_t)(b*F_ + f))*N_ + n] = s * (1.f/3.f);   // transposed [B,F,N]
    }
}

// ---------------------------------------------------------------------------
// Suffix scan over node groups: Tnext[b,n,f] = sum_{n' > n} G[b,n',f].
// One wave per (b,f); lane l owns groups l*8..l*8+7. G_t is [B,F,N] so the
// 8 loads per lane are two coalesced float4s.
// ---------------------------------------------------------------------------
__global__ __launch_bounds__(256)
void scan_kernel(const float* __restrict__ G_t, float* __restrict__ Tnext)
{
    const int gtid = blockIdx.x * 256 + threadIdx.x;
    const int wv   = gtid >> 6;           // 0..511 = (b,f)
    const int lane = threadIdx.x & 63;
    const int b = wv >> 6;
    const int f = wv & 63;

    const float* g = G_t + ((size_t)(b*F_ + f))*N_ + lane*8;
    const float4 g0 = *(const float4*)g;
    const float4 g1 = *(const float4*)(g + 4);
    const float gv[8] = {g0.x,g0.y,g0.z,g0.w, g1.x,g1.y,g1.z,g1.w};
    float s[9];
    s[8] = 0.f;
    #pragma unroll
    for (int j = 7; j >= 0; --j) s[j] = s[j+1] + gv[j];

    float x = s[0];
    const float lsum = x;
    #pragma unroll
    for (int off = 1; off < 64; off <<= 1) {
        float t = __shfl_down(x, off);
        if (lane + off < 64) x += t;      // inclusive suffix sum across lanes
    }
    const float excl = x - lsum;          // sum over lanes > lane

    float* outp = Tnext + ((size_t)(b*N_ + lane*8))*F_ + f;
    #pragma unroll
    for (int j = 0; j < 8; ++j) outp[(size_t)j*F_] = excl + s[j+1];
}

// ---------------------------------------------------------------------------
// node_hat[b,n,f] = sum_c softmax_c(agg[b,n,:]) * upward[b, n*8+c, f]
// upward recomputed from Tnext + within-group running suffix of interp.
// ---------------------------------------------------------------------------
__global__ __launch_bounds__(64)
void node_hat_kernel(const float* __restrict__ Tnext, const float* __restrict__ agg,
                     const float* __restrict__ leaf_v, const float* __restrict__ node_v,
                     const float* __restrict__ root, float* __restrict__ node_hat)
{
    const int bn = blockIdx.x;
    const int b = bn >> 9;
    const int n = bn & (N_ - 1);
    const int f = threadIdx.x;

    float a[8];
    #pragma unroll
    for (int c = 0; c < 8; ++c) a[c] = agg[(size_t)b*L_ + n*8 + c];
    float mx = a[0];
    #pragma unroll
    for (int c = 1; c < 8; ++c) mx = fmaxf(mx, a[c]);
    float wgt[8]; float wsum = 0.f;
    #pragma unroll
    for (int c = 0; c < 8; ++c) { wgt[c] = __expf(a[c] - mx); wsum += wgt[c]; }

    const float tn    = Tnext[(size_t)bn*F_ + f];
    const float rootf = root[b*F_ + f];
    const float nv    = node_v[(size_t)bn*F_ + f];
    float run = 0.f, acc = 0.f;
    #pragma unroll
    for (int c = 7; c >= 0; --c) {
        const int l = n*8 + c;
        const float interp = (rootf + nv + leaf_v[((size_t)b*L_ + l)*F_ + f]) * (1.f/3.f);
        run += interp;
        const float up = (tn + run) / (float)(L_ - l);
        acc = fmaf(wgt[c], up, acc);
    }
    node_hat[(size_t)bn*F_ + f] = acc / wsum;
}

// ---------------------------------------------------------------------------
// Fused dual-softmax attention + final feature softmax.
// Block = (b, 32 targets), 256 threads. Single pass over M = 512 node rows
// then 4096 leaf rows in 64-row tiles; separate exp-sum per region (logits are
// small, no max subtraction needed). LDS strides 68/65 chosen so strided-row
// reads hit distinct banks (G4).
// ---------------------------------------------------------------------------
__device__ __forceinline__ void pv_accum(const float* __restrict__ Ps, const float* __restrict__ Vs,
                                         int tP, int f0, float (&acc)[8])
{
    #pragma unroll
    for (int m = 0; m < 64; ++m) {
        const float pm = Ps[tP*65 + m];
        const float4 v0 = *(const float4*)(Vs + m*F_ + f0);
        const float4 v1 = *(const float4*)(Vs + m*F_ + f0 + 4);
        acc[0] = fmaf(pm, v0.x, acc[0]);
        acc[1] = fmaf(pm, v0.y, acc[1]);
        acc[2] = fmaf(pm, v0.z, acc[2]);
        acc[3] = fmaf(pm, v0.w, acc[3]);
        acc[4] = fmaf(pm, v1.x, acc[4]);
        acc[5] = fmaf(pm, v1.y, acc[5]);
        acc[6] = fmaf(pm, v1.z, acc[6]);
        acc[7] = fmaf(pm, v1.w, acc[7]);
    }
}

__global__ __launch_bounds__(256)
void attn_kernel(const float* __restrict__ q, const float* __restrict__ node_k,
                 const float* __restrict__ node_hat, const float* __restrict__ leaf_k,
                 const float* __restrict__ leaf_v, float* __restrict__ out)
{
    __shared__ float Ks[64 * 68];
    __shared__ float Vs[64 * 64];
    __shared__ float Ps[32 * 65];
    __shared__ float dsum[2][32];

    const int tid = threadIdx.x;
    const int b  = blockIdx.x >> 5;
    const int t0 = (blockIdx.x & 31) * 32;
    const int tP = tid >> 3;        // target row 0..31
    const int jP = tid & 7;
    const int f0 = jP << 3;

    // q row held in registers (64 VGPR)
    float4 qreg[16];
    const float4* qrow = (const float4*)(q + ((size_t)(b*T_ + t0 + tP)) * F_);
    #pragma unroll
    for (int i = 0; i < 16; ++i) qreg[i] = qrow[i];

    if (tid < 64) ((float*)dsum)[tid] = 0.f;

    float accN[8] = {0,0,0,0,0,0,0,0};
    float accL[8] = {0,0,0,0,0,0,0,0};

    const float* Kn = node_k   + (size_t)b*N_*F_;
    const float* Vn = node_hat + (size_t)b*N_*F_;
    const float* Kl = leaf_k   + (size_t)b*L_*F_;
    const float* Vl = leaf_v   + (size_t)b*L_*F_;

    for (int tile = 0; tile < 72; ++tile) {
        const bool isNode = tile < 8;
        const float4* Ksrc = (const float4*)(isNode ? Kn + tile*64*F_ : Kl + (tile-8)*64*F_);
        const float4* Vsrc = (const float4*)(isNode ? Vn + tile*64*F_ : Vl + (tile-8)*64*F_);
        __syncthreads();             // previous tile fully consumed
        #pragma unroll
        for (int i0 = 0; i0 < 4; ++i0) {
            const int i = tid + i0 * 256;
            const int row = i >> 4, col = (i & 15) << 2;
            *(float4*)(Ks + row*68 + col) = Ksrc[i];
            *(float4*)(Vs + row*64 + col) = Vsrc[i];
        }
        __syncthreads();

        // S phase: thread owns (tP, 8 strided m's); q in regs, K rows broadcast
        float p[8] = {0,0,0,0,0,0,0,0};
        #pragma unroll
        for (int ks = 0; ks < 16; ++ks) {
            const float4 qq = qreg[ks];
            #pragma unroll
            for (int mm = 0; mm < 8; ++mm) {
                const float4 kk = *(const float4*)(Ks + (jP + mm*8)*68 + ks*4);
                p[mm] = fmaf(qq.x,kk.x, fmaf(qq.y,kk.y, fmaf(qq.z,kk.z, fmaf(qq.w,kk.w, p[mm]))));
            }
        }
        float psum = 0.f;
        #pragma unroll
        for (int mm = 0; mm < 8; ++mm) {
            p[mm] = __expf(p[mm] * 0.125f);   // scale = 1/sqrt(64)
            psum += p[mm];
            Ps[tP*65 + jP + mm*8] = p[mm];
        }
        psum += __shfl_xor(psum, 1);
        psum += __shfl_xor(psum, 2);
        psum += __shfl_xor(psum, 4);
        if (jP == 0) dsum[isNode ? 0 : 1][tP] += psum;
        __syncthreads();

        // PV phase: thread owns (tP, f0..f0+7)
        if (isNode) pv_accum(Ps, Vs, tP, f0, accN);
        else        pv_accum(Ps, Vs, tP, f0, accL);
    }

    // epilogue: combine regions, softmax over F within the 8-lane tP group
    const float rdn = 1.f / dsum[0][tP];
    const float rdl = 1.f / dsum[1][tP];
    float lg[8];
    #pragma unroll
    for (int u = 0; u < 8; ++u) lg[u] = accN[u]*rdn + accL[u]*rdl;
    float mx = lg[0];
    #pragma unroll
    for (int u = 1; u < 8; ++u) mx = fmaxf(mx, lg[u]);
    mx = fmaxf(mx, __shfl_xor(mx, 1));
    mx = fmaxf(mx, __shfl_xor(mx, 2));
    mx = fmaxf(mx, __shfl_xor(mx, 4));
    float e[8], s = 0.f;
    #pragma unroll
    for (int u = 0; u < 8; ++u) { e[u] = __expf(lg[u] - mx); s += e[u]; }
    s += __shfl_xor(s, 1);
    s += __shfl_xor(s, 2);
    s += __shfl_xor(s, 4);
    const float rs = 1.f / s;
    float4 o0 = make_float4(e[0]*rs, e[1]*rs, e[2]*rs, e[3]*rs);
    float4 o1 = make_float4(e[4]*rs, e[5]*rs, e[6]*rs, e[7]*rs);
    float4* op = (float4*)(out + ((size_t)(b*T_ + t0 + tP))*F_ + f0);
    op[0] = o0;
    op[1] = o1;
}

// ---------------------------------------------------------------------------
extern "C" void kernel_launch(void* const* d_in, const int* in_sizes, int n_in,
                              void* d_out, int out_size, void* d_ws, size_t ws_size,
                              hipStream_t stream)
{
    const float* root   = (const float*)d_in[0];
    const float* node   = (const float*)d_in[1];
    const float* leaf   = (const float*)d_in[2];
    const float* target = (const float*)d_in[3];
    const float* Wq   = (const float*)d_in[4];
    const float* bq   = (const float*)d_in[5];
    const float* Wk   = (const float*)d_in[6];
    const float* bk   = (const float*)d_in[7];
    const float* Wv   = (const float*)d_in[8];
    const float* bv   = (const float*)d_in[9];
    const float* Wagg = (const float*)d_in[10];
    const float* bagg = (const float*)d_in[11];
    float* out = (float*)d_out;

    // workspace layout (floats); total 6,062,080 f32 = 24.2 MB
    float* ws       = (float*)d_ws;
    float* q        = ws;                       // B*T*F   = 524288
    float* node_k   = q       + 524288;         // B*N*F   = 262144
    float* node_v   = node_k  + 262144;
    float* leaf_k   = node_v  + 262144;         // B*L*F   = 2097152
    float* leaf_v   = leaf_k  + 2097152;
    float* agg      = leaf_v  + 2097152;        // B*L     = 32768
    float* G_t      = agg     + 32768;          // B*F*N   = 262144 (transposed)
    float* Tnext    = G_t     + 262144;         // B*N*F
    float* node_hat = Tnext   + 262144;         // B*N*F

    proj_kernel<0,0><<<(B_*T_)/32, 256, 0, stream>>>(target, Wq, bq, q,
        nullptr, nullptr, nullptr, nullptr, nullptr, nullptr,
        nullptr, nullptr, nullptr);
    proj_kernel<1,0><<<(B_*N_)/32, 256, 0, stream>>>(node, Wk, bk, node_k,
        Wv, bv, node_v, nullptr, nullptr, nullptr,
        nullptr, nullptr, nullptr);
    proj_kernel<1,1><<<(B_*L_)/32, 256, 0, stream>>>(leaf, Wk, bk, leaf_k,
        Wv, bv, leaf_v, Wagg, bagg, agg,
        root, node_v, G_t);
    scan_kernel<<<128, 256, 0, stream>>>(G_t, Tnext);
    node_hat_kernel<<<B_*N_, 64, 0, stream>>>(Tnext, agg, leaf_v, node_v, root, node_hat);
    attn_kernel<<<B_*(T_/32), 256, 0, stream>>>(q, node_k, node_hat, leaf_k, leaf_v, out);
}

// Round 2
// 492.378 us; speedup vs baseline: 1.4377x; 1.4377x over previous
//
#include <hip/hip_runtime.h>

// DecoderAttention: B=8, T=1024, N=512, L=4096, D=512, F=64, BR=8
#define B_ 8
#define T_ 1024
#define N_ 512
#define L_ 4096
#define D_ 512
#define F_ 64
#define SLICES 4
#define TPS 18   // tiles per slice (72 total: 8 node + 64 leaf)

// ---------------------------------------------------------------------------
// Projection kernel (unchanged from round 0).
// ---------------------------------------------------------------------------
template<int HAS_V, int HAS_AGG>
__global__ __launch_bounds__(256)
void proj_kernel(const float* __restrict__ X,
                 const float* __restrict__ Wk, const float* __restrict__ bk, float* __restrict__ outK,
                 const float* __restrict__ Wv, const float* __restrict__ bv, float* __restrict__ outV,
                 const float* __restrict__ Wagg, const float* __restrict__ bagg, float* __restrict__ outAgg,
                 const float* __restrict__ root, const float* __restrict__ node_v, float* __restrict__ G_t)
{
    __shared__ float Xs[32 * D_];   // 64 KB
    const int tid = threadIdx.x;
    const int r0  = blockIdx.x * 32;

    const float4* src = (const float4*)(X + (size_t)r0 * D_);
    float4* dst = (float4*)Xs;
    #pragma unroll
    for (int i = 0; i < 16; ++i) dst[tid + i * 256] = src[tid + i * 256];
    __syncthreads();

    const int w = tid >> 6;
    const int f = tid & 63;
    const float* xbase = Xs + w * 8 * D_;

    float accK[8] = {0,0,0,0,0,0,0,0};
    float accV[8] = {0,0,0,0,0,0,0,0};

    for (int d = 0; d < D_; d += 4) {
        const float k0 = Wk[(d+0)*F_ + f];
        const float k1 = Wk[(d+1)*F_ + f];
        const float k2 = Wk[(d+2)*F_ + f];
        const float k3 = Wk[(d+3)*F_ + f];
        float v0 = 0.f, v1 = 0.f, v2 = 0.f, v3 = 0.f;
        if constexpr (HAS_V) {
            v0 = Wv[(d+0)*F_ + f]; v1 = Wv[(d+1)*F_ + f];
            v2 = Wv[(d+2)*F_ + f]; v3 = Wv[(d+3)*F_ + f];
        }
        #pragma unroll
        for (int r = 0; r < 8; ++r) {
            const float4 x = *(const float4*)(xbase + r * D_ + d);  // broadcast read
            accK[r] = fmaf(x.x,k0, fmaf(x.y,k1, fmaf(x.z,k2, fmaf(x.w,k3, accK[r]))));
            if constexpr (HAS_V)
                accV[r] = fmaf(x.x,v0, fmaf(x.y,v1, fmaf(x.z,v2, fmaf(x.w,v3, accV[r]))));
        }
    }

    const float bkf = bk[f];
    float bvf = 0.f;
    if constexpr (HAS_V) bvf = bv[f];
    #pragma unroll
    for (int r = 0; r < 8; ++r) {
        const int row = r0 + w*8 + r;
        outK[(size_t)row * F_ + f] = accK[r] + bkf;
        if constexpr (HAS_V) outV[(size_t)row * F_ + f] = accV[r] + bvf;
    }

    if constexpr (HAS_AGG) {
        const float4 wa0 = *(const float4*)(Wagg + f*8);
        const float4 wa1 = *(const float4*)(Wagg + f*8 + 4);
        const float bagg0 = bagg[0];
        #pragma unroll
        for (int r = 0; r < 8; ++r) {
            const float4 x0 = *(const float4*)(xbase + r*D_ + f*8);
            const float4 x1 = *(const float4*)(xbase + r*D_ + f*8 + 4);
            float p = x0.x*wa0.x + x0.y*wa0.y + x0.z*wa0.z + x0.w*wa0.w
                    + x1.x*wa1.x + x1.y*wa1.y + x1.z*wa1.z + x1.w*wa1.w;
            #pragma unroll
            for (int off = 1; off < 64; off <<= 1) p += __shfl_xor(p, off);
            if (f == 0) outAgg[r0 + w*8 + r] = p + bagg0;
        }
        const int b  = r0 >> 12;
        const int l0 = r0 & (L_ - 1);
        const int n  = (l0 >> 3) + w;
        const float rootf = root[b*F_ + f];
        const float nvf   = node_v[((size_t)(b*N_ + n))*F_ + f];
        float s = 0.f;
        #pragma unroll
        for (int r = 0; r < 8; ++r) s += accV[r] + bvf;
        s += 8.f * (rootf + nvf);
        G_t[((size_t)(b*F_ + f))*N_ + n] = s * (1.f/3.f);
    }
}

// ---------------------------------------------------------------------------
// Suffix scan over node groups (unchanged).
// ---------------------------------------------------------------------------
__global__ __launch_bounds__(256)
void scan_kernel(const float* __restrict__ G_t, float* __restrict__ Tnext)
{
    const int gtid = blockIdx.x * 256 + threadIdx.x;
    const int wv   = gtid >> 6;
    const int lane = threadIdx.x & 63;
    const int b = wv >> 6;
    const int f = wv & 63;

    const float* g = G_t + ((size_t)(b*F_ + f))*N_ + lane*8;
    const float4 g0 = *(const float4*)g;
    const float4 g1 = *(const float4*)(g + 4);
    const float gv[8] = {g0.x,g0.y,g0.z,g0.w, g1.x,g1.y,g1.z,g1.w};
    float s[9];
    s[8] = 0.f;
    #pragma unroll
    for (int j = 7; j >= 0; --j) s[j] = s[j+1] + gv[j];

    float x = s[0];
    const float lsum = x;
    #pragma unroll
    for (int off = 1; off < 64; off <<= 1) {
        float t = __shfl_down(x, off);
        if (lane + off < 64) x += t;
    }
    const float excl = x - lsum;

    float* outp = Tnext + ((size_t)(b*N_ + lane*8))*F_ + f;
    #pragma unroll
    for (int j = 0; j < 8; ++j) outp[(size_t)j*F_] = excl + s[j+1];
}

// ---------------------------------------------------------------------------
// node_hat (unchanged).
// ---------------------------------------------------------------------------
__global__ __launch_bounds__(64)
void node_hat_kernel(const float* __restrict__ Tnext, const float* __restrict__ agg,
                     const float* __restrict__ leaf_v, const float* __restrict__ node_v,
                     const float* __restrict__ root, float* __restrict__ node_hat)
{
    const int bn = blockIdx.x;
    const int b = bn >> 9;
    const int n = bn & (N_ - 1);
    const int f = threadIdx.x;

    float a[8];
    #pragma unroll
    for (int c = 0; c < 8; ++c) a[c] = agg[(size_t)b*L_ + n*8 + c];
    float mx = a[0];
    #pragma unroll
    for (int c = 1; c < 8; ++c) mx = fmaxf(mx, a[c]);
    float wgt[8]; float wsum = 0.f;
    #pragma unroll
    for (int c = 0; c < 8; ++c) { wgt[c] = __expf(a[c] - mx); wsum += wgt[c]; }

    const float tn    = Tnext[(size_t)bn*F_ + f];
    const float rootf = root[b*F_ + f];
    const float nv    = node_v[(size_t)bn*F_ + f];
    float run = 0.f, acc = 0.f;
    #pragma unroll
    for (int c = 7; c >= 0; --c) {
        const int l = n*8 + c;
        const float interp = (rootf + nv + leaf_v[((size_t)b*L_ + l)*F_ + f]) * (1.f/3.f);
        run += interp;
        const float up = (tn + run) / (float)(L_ - l);
        acc = fmaf(wgt[c], up, acc);
    }
    node_hat[(size_t)bn*F_ + f] = acc / wsum;
}

// ---------------------------------------------------------------------------
// Sliced dual-softmax attention. Block = (b, slice, 32 targets), 256 thr.
// Each block covers 18 of 72 M-tiles, writes partial PV accumulators +
// partial exp-sums; combine_kernel finishes. Shared 64x68 LDS buffer holds
// K then V per tile (4 barriers/tile); P passes S->PV via __shfl.
// ---------------------------------------------------------------------------
__device__ __forceinline__ void pv_accum(const float* __restrict__ Bs, const float (&p)[8],
                                         int tPl, int jP, float (&acc)[8])
{
    const float* vb = Bs + jP*8;
    #pragma unroll
    for (int mm = 0; mm < 8; ++mm) {
        #pragma unroll
        for (int mj = 0; mj < 8; ++mj) {
            const float pm = __shfl(p[mm], (tPl<<3) | mj, 64);
            const int m = (mm<<3) | mj;
            const float4 v0 = *(const float4*)(vb + m*68);
            const float4 v1 = *(const float4*)(vb + m*68 + 4);
            acc[0] = fmaf(pm, v0.x, acc[0]);
            acc[1] = fmaf(pm, v0.y, acc[1]);
            acc[2] = fmaf(pm, v0.z, acc[2]);
            acc[3] = fmaf(pm, v0.w, acc[3]);
            acc[4] = fmaf(pm, v1.x, acc[4]);
            acc[5] = fmaf(pm, v1.y, acc[5]);
            acc[6] = fmaf(pm, v1.z, acc[6]);
            acc[7] = fmaf(pm, v1.w, acc[7]);
        }
    }
}

__global__ __launch_bounds__(256, 4)
void attn_kernel(const float* __restrict__ q, const float* __restrict__ node_k,
                 const float* __restrict__ node_hat, const float* __restrict__ leaf_k,
                 const float* __restrict__ leaf_v,
                 float* __restrict__ pacc, float* __restrict__ pd)
{
    __shared__ float Bs[64 * 68];   // 17.4 KB, shared K-then-V buffer

    // XCD-aware swizzle: 1024 blocks, 8 XCDs -> each XCD gets 4 (b,slice)
    // groups whose K/V slice (~0.6MB each) stays L2-local.
    const int wg  = (blockIdx.x & 7) * (1024/8) + (blockIdx.x >> 3);
    const int t0b = wg & 31;
    const int s   = (wg >> 5) & (SLICES-1);
    const int b   = wg >> 7;
    const int t0  = t0b * 32;

    const int tid = threadIdx.x;
    const int tP  = tid >> 3;        // target row 0..31
    const int jP  = tid & 7;
    const int tPl = (tid & 63) >> 3; // tP within wave

    float4 qreg[16];
    const float4* qrow = (const float4*)(q + ((size_t)(b*T_ + t0 + tP)) * F_);
    #pragma unroll
    for (int i = 0; i < 16; ++i) qreg[i] = qrow[i];

    float accN[8] = {0,0,0,0,0,0,0,0};
    float accL[8] = {0,0,0,0,0,0,0,0};
    float dsumN = 0.f, dsumL = 0.f;

    const float* Kn = node_k   + (size_t)b*N_*F_;
    const float* Vn = node_hat + (size_t)b*N_*F_;
    const float* Kl = leaf_k   + (size_t)b*L_*F_;
    const float* Vl = leaf_v   + (size_t)b*L_*F_;

    for (int ti = s*TPS; ti < s*TPS + TPS; ++ti) {
        const bool isNode = ti < 8;
        const float4* Ksrc = (const float4*)(isNode ? Kn + ti*64*F_ : Kl + (ti-8)*64*F_);
        const float4* Vsrc = (const float4*)(isNode ? Vn + ti*64*F_ : Vl + (ti-8)*64*F_);

        __syncthreads();            // previous PV done with Bs
        #pragma unroll
        for (int i0 = 0; i0 < 4; ++i0) {
            const int i = tid + i0 * 256;
            *(float4*)(Bs + (i >> 4)*68 + (i & 15)*4) = Ksrc[i];
        }
        __syncthreads();

        // S phase: thread (tP, jP) covers m = jP + 8*mm
        float p[8] = {0,0,0,0,0,0,0,0};
        #pragma unroll
        for (int ks = 0; ks < 16; ++ks) {
            const float4 qq = qreg[ks];
            #pragma unroll
            for (int mm = 0; mm < 8; ++mm) {
                const float4 kk = *(const float4*)(Bs + (jP + mm*8)*68 + ks*4);
                p[mm] = fmaf(qq.x,kk.x, fmaf(qq.y,kk.y, fmaf(qq.z,kk.z, fmaf(qq.w,kk.w, p[mm]))));
            }
        }
        float psum = 0.f;
        #pragma unroll
        for (int mm = 0; mm < 8; ++mm) {
            p[mm] = __expf(p[mm] * 0.125f);   // scale = 1/sqrt(64)
            psum += p[mm];
        }
        if (isNode) dsumN += psum; else dsumL += psum;

        __syncthreads();            // done reading K
        #pragma unroll
        for (int i0 = 0; i0 < 4; ++i0) {
            const int i = tid + i0 * 256;
            *(float4*)(Bs + (i >> 4)*68 + (i & 15)*4) = Vsrc[i];
        }
        __syncthreads();

        if (isNode) pv_accum(Bs, p, tPl, jP, accN);
        else        pv_accum(Bs, p, tPl, jP, accL);
    }

    // reduce region denominators across the 8 jP lanes (same tP group)
    #pragma unroll
    for (int off = 1; off < 8; off <<= 1) {
        dsumN += __shfl_xor(dsumN, off);
        dsumL += __shfl_xor(dsumL, off);
    }

    const int gt = b*T_ + t0 + tP;
    float* pN = pacc + (((size_t)s*(B_*T_) + gt)*2 + 0)*F_ + jP*8;
    float* pL = pacc + (((size_t)s*(B_*T_) + gt)*2 + 1)*F_ + jP*8;
    *(float4*)(pN)     = make_float4(accN[0],accN[1],accN[2],accN[3]);
    *(float4*)(pN + 4) = make_float4(accN[4],accN[5],accN[6],accN[7]);
    *(float4*)(pL)     = make_float4(accL[0],accL[1],accL[2],accL[3]);
    *(float4*)(pL + 4) = make_float4(accL[4],accL[5],accL[6],accL[7]);
    if (jP == 0) {
        pd[((size_t)s*(B_*T_) + gt)*2 + 0] = dsumN;
        pd[((size_t)s*(B_*T_) + gt)*2 + 1] = dsumL;
    }
}

// ---------------------------------------------------------------------------
// Combine slices + final feature softmax. One wave per target, lane = f.
// ---------------------------------------------------------------------------
__global__ __launch_bounds__(256)
void combine_kernel(const float* __restrict__ pacc, const float* __restrict__ pd,
                    float* __restrict__ out)
{
    const int gt = (blockIdx.x * 256 + threadIdx.x) >> 6;
    const int f  = threadIdx.x & 63;

    float aN = 0.f, aL = 0.f, dN = 0.f, dL = 0.f;
    #pragma unroll
    for (int s = 0; s < SLICES; ++s) {
        const size_t base = ((size_t)s*(B_*T_) + gt)*2;
        aN += pacc[(base + 0)*F_ + f];
        aL += pacc[(base + 1)*F_ + f];
        dN += pd[base + 0];
        dL += pd[base + 1];
    }
    float lg = aN / dN + aL / dL;
    float mx = lg;
    #pragma unroll
    for (int off = 1; off < 64; off <<= 1) mx = fmaxf(mx, __shfl_xor(mx, off));
    const float e = __expf(lg - mx);
    float ssum = e;
    #pragma unroll
    for (int off = 1; off < 64; off <<= 1) ssum += __shfl_xor(ssum, off);
    out[(size_t)gt*F_ + f] = e / ssum;
}

// ---------------------------------------------------------------------------
extern "C" void kernel_launch(void* const* d_in, const int* in_sizes, int n_in,
                              void* d_out, int out_size, void* d_ws, size_t ws_size,
                              hipStream_t stream)
{
    const float* root   = (const float*)d_in[0];
    const float* node   = (const float*)d_in[1];
    const float* leaf   = (const float*)d_in[2];
    const float* target = (const float*)d_in[3];
    const float* Wq   = (const float*)d_in[4];
    const float* bq   = (const float*)d_in[5];
    const float* Wk   = (const float*)d_in[6];
    const float* bk   = (const float*)d_in[7];
    const float* Wv   = (const float*)d_in[8];
    const float* bv   = (const float*)d_in[9];
    const float* Wagg = (const float*)d_in[10];
    const float* bagg = (const float*)d_in[11];
    float* out = (float*)d_out;

    // workspace layout (floats); ~41.3 MB total
    float* ws       = (float*)d_ws;
    float* q        = ws;                       // B*T*F   = 524288
    float* node_k   = q       + 524288;         // B*N*F   = 262144
    float* node_v   = node_k  + 262144;
    float* leaf_k   = node_v  + 262144;         // B*L*F   = 2097152
    float* leaf_v   = leaf_k  + 2097152;
    float* agg      = leaf_v  + 2097152;        // B*L     = 32768
    float* G_t      = agg     + 32768;          // B*F*N   = 262144
    float* Tnext    = G_t     + 262144;         // B*N*F
    float* node_hat = Tnext   + 262144;         // B*N*F
    float* pacc     = node_hat + 262144;        // SLICES*B*T*2*F = 4194304
    float* pd       = pacc    + (size_t)SLICES*B_*T_*2*F_;  // SLICES*B*T*2 = 65536

    proj_kernel<0,0><<<(B_*T_)/32, 256, 0, stream>>>(target, Wq, bq, q,
        nullptr, nullptr, nullptr, nullptr, nullptr, nullptr,
        nullptr, nullptr, nullptr);
    proj_kernel<1,0><<<(B_*N_)/32, 256, 0, stream>>>(node, Wk, bk, node_k,
        Wv, bv, node_v, nullptr, nullptr, nullptr,
        nullptr, nullptr, nullptr);
    proj_kernel<1,1><<<(B_*L_)/32, 256, 0, stream>>>(leaf, Wk, bk, leaf_k,
        Wv, bv, leaf_v, Wagg, bagg, agg,
        root, node_v, G_t);
    scan_kernel<<<128, 256, 0, stream>>>(G_t, Tnext);
    node_hat_kernel<<<B_*N_, 64, 0, stream>>>(Tnext, agg, leaf_v, node_v, root, node_hat);
    attn_kernel<<<B_*(T_/32)*SLICES, 256, 0, stream>>>(q, node_k, node_hat, leaf_k, leaf_v, pacc, pd);
    combine_kernel<<<(B_*T_)/4, 256, 0, stream>>>(pacc, pd, out);
}

// Round 4
// 203.069 us; speedup vs baseline: 3.4860x; 2.4247x over previous
//
#include <hip/hip_runtime.h>

// DecoderAttention: B=8, T=1024, N=512, L=4096, D=512, F=64, BR=8
#define B_ 8
#define T_ 1024
#define N_ 512
#define L_ 4096
#define D_ 512
#define F_ 64
#define SLICES 4
#define TPS 18    // tiles per slice (72 total: 8 node + 64 leaf)
#define KSTR 72   // LDS row stride (bf16 elements) for K / V^T tiles

typedef __attribute__((ext_vector_type(8))) short short8;
typedef __attribute__((ext_vector_type(4))) float f32x4;

__device__ __forceinline__ unsigned short f2bf(float x){
    unsigned u = __builtin_bit_cast(unsigned, x);
    u += 0x7FFFu + ((u >> 16) & 1u);           // RNE
    return (unsigned short)(u >> 16);
}
__device__ __forceinline__ unsigned pack_bf(float lo, float hi){
    return (unsigned)f2bf(lo) | ((unsigned)f2bf(hi) << 16);
}
__device__ __forceinline__ short8 frag_from4(unsigned d0, unsigned d1, unsigned d2, unsigned d3){
    union { unsigned u[4]; short8 s; } t;
    t.u[0] = d0; t.u[1] = d1; t.u[2] = d2; t.u[3] = d3;
    return t.s;
}

// ---------------------------------------------------------------------------
// Projection. MODE 0: q bf16 (pre-scaled 1/8). MODE 1: node (k bf16, v f32).
// MODE 2: leaf (k bf16, v f32 + TRANSPOSED v bf16 [B][F][L], agg, G_t).
// ---------------------------------------------------------------------------
template<int MODE>
__global__ __launch_bounds__(256)
void proj_kernel(const float* __restrict__ X,
                 const float* __restrict__ Wk, const float* __restrict__ bk,
                 unsigned short* __restrict__ outKb,
                 const float* __restrict__ Wv, const float* __restrict__ bv,
                 float* __restrict__ outV, unsigned short* __restrict__ outVt,
                 const float* __restrict__ Wagg, const float* __restrict__ bagg,
                 float* __restrict__ outAgg,
                 const float* __restrict__ root, const float* __restrict__ node_v,
                 float* __restrict__ G_t)
{
    constexpr bool HAS_V   = (MODE >= 1);
    constexpr bool HAS_AGG = (MODE == 2);
    __shared__ float Xs[32 * D_];   // 64 KB
    const int tid = threadIdx.x;
    const int r0  = blockIdx.x * 32;

    const float4* src = (const float4*)(X + (size_t)r0 * D_);
    float4* dst = (float4*)Xs;
    #pragma unroll
    for (int i = 0; i < 16; ++i) dst[tid + i * 256] = src[tid + i * 256];
    __syncthreads();

    const int w = tid >> 6;
    const int f = tid & 63;
    const float* xbase = Xs + w * 8 * D_;

    float accK[8] = {0,0,0,0,0,0,0,0};
    float accV[8] = {0,0,0,0,0,0,0,0};

    for (int d = 0; d < D_; d += 4) {
        const float k0 = Wk[(d+0)*F_ + f];
        const float k1 = Wk[(d+1)*F_ + f];
        const float k2 = Wk[(d+2)*F_ + f];
        const float k3 = Wk[(d+3)*F_ + f];
        float v0 = 0.f, v1 = 0.f, v2 = 0.f, v3 = 0.f;
        if constexpr (HAS_V) {
            v0 = Wv[(d+0)*F_ + f]; v1 = Wv[(d+1)*F_ + f];
            v2 = Wv[(d+2)*F_ + f]; v3 = Wv[(d+3)*F_ + f];
        }
        #pragma unroll
        for (int r = 0; r < 8; ++r) {
            const float4 x = *(const float4*)(xbase + r * D_ + d);
            accK[r] = fmaf(x.x,k0, fmaf(x.y,k1, fmaf(x.z,k2, fmaf(x.w,k3, accK[r]))));
            if constexpr (HAS_V)
                accV[r] = fmaf(x.x,v0, fmaf(x.y,v1, fmaf(x.z,v2, fmaf(x.w,v3, accV[r]))));
        }
    }

    const float bkf = bk[f];
    float bvf = 0.f;
    if constexpr (HAS_V) bvf = bv[f];
    #pragma unroll
    for (int r = 0; r < 8; ++r) {
        const size_t row = r0 + w*8 + r;
        const float kv = accK[r] + bkf;
        outKb[row * F_ + f] = f2bf(MODE == 0 ? kv * 0.125f : kv);  // fold 1/sqrt(F) into q
        if constexpr (HAS_V) outV[row * F_ + f] = accV[r] + bvf;
    }
    if constexpr (MODE == 2) {
        // V^T bf16 write: thread (w,f) owns 8 consecutive leaves, one uint4
        const int bb = r0 >> 12;
        const int l0 = r0 & (L_ - 1);
        uint4 tw;
        tw.x = pack_bf(accV[0]+bvf, accV[1]+bvf);
        tw.y = pack_bf(accV[2]+bvf, accV[3]+bvf);
        tw.z = pack_bf(accV[4]+bvf, accV[5]+bvf);
        tw.w = pack_bf(accV[6]+bvf, accV[7]+bvf);
        *(uint4*)(outVt + ((size_t)(bb*F_ + f))*L_ + l0 + w*8) = tw;
    }

    if constexpr (HAS_AGG) {
        const float4 wa0 = *(const float4*)(Wagg + f*8);
        const float4 wa1 = *(const float4*)(Wagg + f*8 + 4);
        const float bagg0 = bagg[0];
        #pragma unroll
        for (int r = 0; r < 8; ++r) {
            const float4 x0 = *(const float4*)(xbase + r*D_ + f*8);
            const float4 x1 = *(const float4*)(xbase + r*D_ + f*8 + 4);
            float p = x0.x*wa0.x + x0.y*wa0.y + x0.z*wa0.z + x0.w*wa0.w
                    + x1.x*wa1.x + x1.y*wa1.y + x1.z*wa1.z + x1.w*wa1.w;
            #pragma unroll
            for (int off = 1; off < 64; off <<= 1) p += __shfl_xor(p, off);
            if (f == 0) outAgg[r0 + w*8 + r] = p + bagg0;
        }
        const int b  = r0 >> 12;
        const int l0 = r0 & (L_ - 1);
        const int n  = (l0 >> 3) + w;
        const float rootf = root[b*F_ + f];
        const float nvf   = node_v[((size_t)(b*N_ + n))*F_ + f];
        float s = 0.f;
        #pragma unroll
        for (int r = 0; r < 8; ++r) s += accV[r] + bvf;
        s += 8.f * (rootf + nvf);
        G_t[((size_t)(b*F_ + f))*N_ + n] = s * (1.f/3.f);
    }
}

// ---------------------------------------------------------------------------
// Suffix scan over node groups (unchanged).
// ---------------------------------------------------------------------------
__global__ __launch_bounds__(256)
void scan_kernel(const float* __restrict__ G_t, float* __restrict__ Tnext)
{
    const int gtid = blockIdx.x * 256 + threadIdx.x;
    const int wv   = gtid >> 6;
    const int lane = threadIdx.x & 63;
    const int b = wv >> 6;
    const int f = wv & 63;

    const float* g = G_t + ((size_t)(b*F_ + f))*N_ + lane*8;
    const float4 g0 = *(const float4*)g;
    const float4 g1 = *(const float4*)(g + 4);
    const float gv[8] = {g0.x,g0.y,g0.z,g0.w, g1.x,g1.y,g1.z,g1.w};
    float s[9];
    s[8] = 0.f;
    #pragma unroll
    for (int j = 7; j >= 0; --j) s[j] = s[j+1] + gv[j];

    float x = s[0];
    const float lsum = x;
    #pragma unroll
    for (int off = 1; off < 64; off <<= 1) {
        float t = __shfl_down(x, off);
        if (lane + off < 64) x += t;
    }
    const float excl = x - lsum;

    float* outp = Tnext + ((size_t)(b*N_ + lane*8))*F_ + f;
    #pragma unroll
    for (int j = 0; j < 8; ++j) outp[(size_t)j*F_] = excl + s[j+1];
}

// ---------------------------------------------------------------------------
// node_hat -> TRANSPOSED bf16 [B][F][N] (feeds attention node-region V^T).
// ---------------------------------------------------------------------------
__global__ __launch_bounds__(64)
void node_hat_kernel(const float* __restrict__ Tnext, const float* __restrict__ agg,
                     const float* __restrict__ leaf_v, const float* __restrict__ node_v,
                     const float* __restrict__ root, unsigned short* __restrict__ nh_t)
{
    const int bn = blockIdx.x;
    const int b = bn >> 9;
    const int n = bn & (N_ - 1);
    const int f = threadIdx.x;

    float a[8];
    #pragma unroll
    for (int c = 0; c < 8; ++c) a[c] = agg[(size_t)b*L_ + n*8 + c];
    float mx = a[0];
    #pragma unroll
    for (int c = 1; c < 8; ++c) mx = fmaxf(mx, a[c]);
    float wgt[8]; float wsum = 0.f;
    #pragma unroll
    for (int c = 0; c < 8; ++c) { wgt[c] = __expf(a[c] - mx); wsum += wgt[c]; }

    const float tn    = Tnext[(size_t)bn*F_ + f];
    const float rootf = root[b*F_ + f];
    const float nv    = node_v[(size_t)bn*F_ + f];
    float run = 0.f, acc = 0.f;
    #pragma unroll
    for (int c = 7; c >= 0; --c) {
        const int l = n*8 + c;
        const float interp = (rootf + nv + leaf_v[((size_t)b*L_ + l)*F_ + f]) * (1.f/3.f);
        run += interp;
        const float up = (tn + run) / (float)(L_ - l);
        acc = fmaf(wgt[c], up, acc);
    }
    nh_t[((size_t)(b*F_ + f))*N_ + n] = f2bf(acc / wsum);
}

// ---------------------------------------------------------------------------
// MFMA dual-softmax attention, transpose-free.
// Block = (b, slice, 64 targets), 4 waves x 16 targets. Per 64-row M-tile:
//   S^T = K.Q^T : A=K rows (LDS, contiguous), B=q regs        (8 mfma)
//   lane (c,h) holds P[t'=c][m=16ss+4h+r]; exp in-register
//   B-frag (P^T) built via 16 __shfl + cndmask (in-register transpose)
//   out^T += V^T.P^T : A=V^T rows (LDS, contiguous)           (8 mfma)
// V^T comes pre-transposed from global ([B][F][L] / [B][F][N]).
// ---------------------------------------------------------------------------
__global__ __launch_bounds__(256, 2)
void attn_kernel(const unsigned short* __restrict__ qb,
                 const unsigned short* __restrict__ nk,
                 const unsigned short* __restrict__ nht,
                 const unsigned short* __restrict__ lk,
                 const unsigned short* __restrict__ lvt,
                 float* __restrict__ pacc, float* __restrict__ pd)
{
    __shared__ unsigned short Ks[2][64*KSTR];   // 18 KB
    __shared__ unsigned short Vt[2][64*KSTR];   // 18 KB

    // XCD swizzle: 512 blocks, one batch per XCD (bf16 K/V ~1.2 MB -> L2-fits)
    const int wg  = (blockIdx.x & 7) * 64 + (blockIdx.x >> 3);
    const int b   = wg >> 6;
    const int sl  = (wg >> 4) & 3;
    const int t0  = (wg & 15) * 64;

    const int tid = threadIdx.x;
    const int w   = tid >> 6;
    const int l   = tid & 63;
    const int c   = l & 15;
    const int h   = l >> 4;
    const int sm  = tid >> 2;      // staging row
    const int sc  = tid & 3;       // staging 16-col chunk

    // q fragment: lane (c,h) holds q[t0+w*16+c][8h..8h+7 (+32)]
    const unsigned short* qrow = qb + ((size_t)(b*T_ + t0 + w*16 + c))*F_ + 8*h;
    const short8 qf0 = *(const short8*)qrow;
    const short8 qf1 = *(const short8*)(qrow + 32);

    f32x4 accN[4] = {{0,0,0,0},{0,0,0,0},{0,0,0,0},{0,0,0,0}};
    f32x4 accL[4] = {{0,0,0,0},{0,0,0,0},{0,0,0,0},{0,0,0,0}};
    float dsN = 0.f, dsL = 0.f;

    const unsigned short* Knb = nk  + (size_t)b*N_*F_;
    const unsigned short* Klb = lk  + (size_t)b*L_*F_;
    const unsigned short* Vnb = nht + (size_t)b*F_*N_;   // [F][N]
    const unsigned short* Vlb = lvt + (size_t)b*F_*L_;   // [F][L]

    const int ti0 = sl * TPS;

    uint4 sk0, sk1, sv0, sv1;
    auto load_tile = [&](int ti) {
        if (ti < 8) {
            const unsigned short* Kb = Knb + (size_t)ti*64*F_;
            sk0 = *(const uint4*)(Kb + sm*64 + sc*16);
            sk1 = *(const uint4*)(Kb + sm*64 + sc*16 + 8);
            const unsigned short* Vb = Vnb + (size_t)sm*N_ + ti*64;
            sv0 = *(const uint4*)(Vb + sc*16);
            sv1 = *(const uint4*)(Vb + sc*16 + 8);
        } else {
            const unsigned short* Kb = Klb + (size_t)(ti-8)*64*F_;
            sk0 = *(const uint4*)(Kb + sm*64 + sc*16);
            sk1 = *(const uint4*)(Kb + sm*64 + sc*16 + 8);
            const unsigned short* Vb = Vlb + (size_t)sm*L_ + (ti-8)*64;
            sv0 = *(const uint4*)(Vb + sc*16);
            sv1 = *(const uint4*)(Vb + sc*16 + 8);
        }
    };
    auto write_tile = [&](int pb) {
        *(uint4*)&Ks[pb][sm*KSTR + sc*16]     = sk0;
        *(uint4*)&Ks[pb][sm*KSTR + sc*16 + 8] = sk1;
        *(uint4*)&Vt[pb][sm*KSTR + sc*16]     = sv0;
        *(uint4*)&Vt[pb][sm*KSTR + sc*16 + 8] = sv1;
    };

    load_tile(ti0);
    write_tile(0);
    __syncthreads();

    // P-exchange source lanes (derived; see analysis): dwords 0-1 from srcA,
    // 2-3 from srcB; register index selected by hs = h>>1.
    const int srcA = c + 16*((2*h) & 3);
    const int srcB = c + 16*((2*h + 1) & 3);
    const int hs   = h >> 1;

    for (int i = 0; i < TPS; ++i) {
        const int  ti  = ti0 + i;
        const bool isN = ti < 8;
        const int  pb  = i & 1;
        const bool nxt = (i + 1 < TPS);
        if (nxt) load_tile(ti + 1);          // issue next-tile loads early

        // ---- S^T = K.Q^T : lane (c,h) -> P[t'=c][m=16ss+4h+r] ----
        f32x4 st[4] = {{0,0,0,0},{0,0,0,0},{0,0,0,0},{0,0,0,0}};
        #pragma unroll
        for (int ss = 0; ss < 4; ++ss) {
            const short8 kf0 = *(const short8*)&Ks[pb][(16*ss + c)*KSTR + 8*h];
            st[ss] = __builtin_amdgcn_mfma_f32_16x16x32_bf16(kf0, qf0, st[ss], 0,0,0);
            const short8 kf1 = *(const short8*)&Ks[pb][(16*ss + c)*KSTR + 32 + 8*h];
            st[ss] = __builtin_amdgcn_mfma_f32_16x16x32_bf16(kf1, qf1, st[ss], 0,0,0);
        }

        // ---- exp (in-register), bf16 pack, lane-local denominator ----
        unsigned pk0[4], pk1[4];
        float psum = 0.f;
        #pragma unroll
        for (int ss = 0; ss < 4; ++ss) {
            #pragma unroll
            for (int r = 0; r < 4; ++r) { st[ss][r] = __expf(st[ss][r]); psum += st[ss][r]; }
            pk0[ss] = pack_bf(st[ss][0], st[ss][1]);   // m = 16ss+4h+{0,1}
            pk1[ss] = pack_bf(st[ss][2], st[ss][3]);   // m = 16ss+4h+{2,3}
        }
        if (isN) dsN += psum; else dsL += psum;

        // ---- out^T += V^T.P^T ----
        #pragma unroll
        for (int k00 = 0; k00 < 2; ++k00) {      // k0 = 32*k00
            const unsigned d0a = __shfl(pk0[2*k00+0], srcA);
            const unsigned d0b = __shfl(pk0[2*k00+1], srcA);
            const unsigned d1a = __shfl(pk1[2*k00+0], srcA);
            const unsigned d1b = __shfl(pk1[2*k00+1], srcA);
            const unsigned d2a = __shfl(pk0[2*k00+0], srcB);
            const unsigned d2b = __shfl(pk0[2*k00+1], srcB);
            const unsigned d3a = __shfl(pk1[2*k00+0], srcB);
            const unsigned d3b = __shfl(pk1[2*k00+1], srcB);
            const short8 bp = frag_from4(hs ? d0b : d0a, hs ? d1b : d1a,
                                         hs ? d2b : d2a, hs ? d3b : d3a);
            if (isN) {
                #pragma unroll
                for (int s2 = 0; s2 < 4; ++s2) {
                    const short8 af = *(const short8*)&Vt[pb][(16*s2 + c)*KSTR + 32*k00 + 8*h];
                    accN[s2] = __builtin_amdgcn_mfma_f32_16x16x32_bf16(af, bp, accN[s2], 0,0,0);
                }
            } else {
                #pragma unroll
                for (int s2 = 0; s2 < 4; ++s2) {
                    const short8 af = *(const short8*)&Vt[pb][(16*s2 + c)*KSTR + 32*k00 + 8*h];
                    accL[s2] = __builtin_amdgcn_mfma_f32_16x16x32_bf16(af, bp, accL[s2], 0,0,0);
                }
            }
        }

        if (nxt) {
            write_tile(pb ^ 1);
            __syncthreads();
        }
    }

    // ---- denominators: deferred reduction over the 4 h-groups ----
    dsN += __shfl_xor(dsN, 16);  dsN += __shfl_xor(dsN, 32);
    dsL += __shfl_xor(dsL, 16);  dsL += __shfl_xor(dsL, 32);

    // ---- store partials: lane (c,h) owns t'=c, f = 16*s2+4h+r ----
    const int gt = b*T_ + t0 + w*16 + c;
    float* baseN = pacc + (((size_t)sl*(B_*T_) + gt)*2 + 0)*F_;
    float* baseL = baseN + F_;
    #pragma unroll
    for (int s2 = 0; s2 < 4; ++s2) {
        #pragma unroll
        for (int r = 0; r < 4; ++r) {
            baseN[s2*16 + 4*h + r] = accN[s2][r];
            baseL[s2*16 + 4*h + r] = accL[s2][r];
        }
    }
    if (h == 0) {
        pd[((size_t)sl*(B_*T_) + gt)*2 + 0] = dsN;
        pd[((size_t)sl*(B_*T_) + gt)*2 + 1] = dsL;
    }
}

// ---------------------------------------------------------------------------
// Combine slices + final feature softmax. One wave per target, lane = f.
// ---------------------------------------------------------------------------
__global__ __launch_bounds__(256)
void combine_kernel(const float* __restrict__ pacc, const float* __restrict__ pd,
                    float* __restrict__ out)
{
    const int gt = (blockIdx.x * 256 + threadIdx.x) >> 6;
    const int f  = threadIdx.x & 63;

    float aN = 0.f, aL = 0.f, dN = 0.f, dL = 0.f;
    #pragma unroll
    for (int s = 0; s < SLICES; ++s) {
        const size_t base = ((size_t)s*(B_*T_) + gt)*2;
        aN += pacc[(base + 0)*F_ + f];
        aL += pacc[(base + 1)*F_ + f];
        dN += pd[base + 0];
        dL += pd[base + 1];
    }
    float lg = aN / dN + aL / dL;
    float mx = lg;
    #pragma unroll
    for (int off = 1; off < 64; off <<= 1) mx = fmaxf(mx, __shfl_xor(mx, off));
    const float e = __expf(lg - mx);
    float ssum = e;
    #pragma unroll
    for (int off = 1; off < 64; off <<= 1) ssum += __shfl_xor(ssum, off);
    out[(size_t)gt*F_ + f] = e / ssum;
}

// ---------------------------------------------------------------------------
extern "C" void kernel_launch(void* const* d_in, const int* in_sizes, int n_in,
                              void* d_out, int out_size, void* d_ws, size_t ws_size,
                              hipStream_t stream)
{
    const float* root   = (const float*)d_in[0];
    const float* node   = (const float*)d_in[1];
    const float* leaf   = (const float*)d_in[2];
    const float* target = (const float*)d_in[3];
    const float* Wq   = (const float*)d_in[4];
    const float* bq   = (const float*)d_in[5];
    const float* Wk   = (const float*)d_in[6];
    const float* bk   = (const float*)d_in[7];
    const float* Wv   = (const float*)d_in[8];
    const float* bv   = (const float*)d_in[9];
    const float* Wagg = (const float*)d_in[10];
    const float* bagg = (const float*)d_in[11];
    float* out = (float*)d_out;

    // workspace layout (bytes), ~37 MB
    char* wp = (char*)d_ws;
    unsigned short* q_bf   = (unsigned short*)wp; wp += (size_t)B_*T_*F_*2;   // 1 MB
    unsigned short* nk_bf  = (unsigned short*)wp; wp += (size_t)B_*N_*F_*2;   // 0.5 MB
    unsigned short* lk_bf  = (unsigned short*)wp; wp += (size_t)B_*L_*F_*2;   // 4 MB
    unsigned short* lvt_bf = (unsigned short*)wp; wp += (size_t)B_*F_*L_*2;   // 4 MB (transposed)
    unsigned short* nht_bf = (unsigned short*)wp; wp += (size_t)B_*F_*N_*2;   // 0.5 MB (transposed)
    float* node_v = (float*)wp; wp += (size_t)B_*N_*F_*4;                     // 1 MB
    float* leaf_v = (float*)wp; wp += (size_t)B_*L_*F_*4;                     // 8 MB
    float* agg    = (float*)wp; wp += (size_t)B_*L_*4;                        // 128 KB
    float* G_t    = (float*)wp; wp += (size_t)B_*F_*N_*4;                     // 1 MB
    float* Tnext  = (float*)wp; wp += (size_t)B_*N_*F_*4;                     // 1 MB
    float* pacc   = (float*)wp; wp += (size_t)SLICES*B_*T_*2*F_*4;            // 16 MB
    float* pd     = (float*)wp;                                               // 256 KB

    proj_kernel<0><<<(B_*T_)/32, 256, 0, stream>>>(target, Wq, bq, q_bf,
        nullptr, nullptr, nullptr, nullptr, nullptr, nullptr, nullptr,
        nullptr, nullptr, nullptr);
    proj_kernel<1><<<(B_*N_)/32, 256, 0, stream>>>(node, Wk, bk, nk_bf,
        Wv, bv, node_v, nullptr, nullptr, nullptr, nullptr,
        nullptr, nullptr, nullptr);
    proj_kernel<2><<<(B_*L_)/32, 256, 0, stream>>>(leaf, Wk, bk, lk_bf,
        Wv, bv, leaf_v, lvt_bf, Wagg, bagg, agg,
        root, node_v, G_t);
    scan_kernel<<<128, 256, 0, stream>>>(G_t, Tnext);
    node_hat_kernel<<<B_*N_, 64, 0, stream>>>(Tnext, agg, leaf_v, node_v, root, nht_bf);
    attn_kernel<<<B_*(T_/64)*SLICES, 256, 0, stream>>>(q_bf, nk_bf, nht_bf, lk_bf, lvt_bf, pacc, pd);
    combine_kernel<<<(B_*T_)/4, 256, 0, stream>>>(pacc, pd, out);
}

// Round 5
// 135.940 us; speedup vs baseline: 5.2075x; 1.4938x over previous
//
#include <hip/hip_runtime.h>

// DecoderAttention: B=8, T=1024, N=512, L=4096, D=512, F=64, BR=8
#define B_ 8
#define T_ 1024
#define N_ 512
#define L_ 4096
#define D_ 512
#define F_ 64
#define SLICES 4
#define TPS 18    // tiles per slice (72 total: 8 node + 64 leaf)
#define KSTR 72   // attn LDS row stride (bf16) for K / V^T tiles
#define XSTR 520  // proj LDS row stride (bf16): 1040B -> 4-bank rotation, 2-way max

typedef __attribute__((ext_vector_type(8))) short short8;
typedef __attribute__((ext_vector_type(4))) float f32x4;

__device__ __forceinline__ unsigned short f2bf(float x){
    unsigned u = __builtin_bit_cast(unsigned, x);
    u += 0x7FFFu + ((u >> 16) & 1u);           // RNE
    return (unsigned short)(u >> 16);
}
__device__ __forceinline__ unsigned pack_bf(float lo, float hi){
    return (unsigned)f2bf(lo) | ((unsigned)f2bf(hi) << 16);
}
__device__ __forceinline__ float bf2f(short s){
    return __builtin_bit_cast(float, ((unsigned)(unsigned short)s) << 16);
}
__device__ __forceinline__ short8 frag_from4(unsigned d0, unsigned d1, unsigned d2, unsigned d3){
    union { unsigned u[4]; short8 s; } t;
    t.u[0] = d0; t.u[1] = d1; t.u[2] = d2; t.u[3] = d3;
    return t.s;
}

// ---------------------------------------------------------------------------
// Weight prep: transposed bf16 weights + bias vectors.
// Wq_t[64][512] (x0.125 folded), Wkv_t[128][512] = [Wk cols | Wv cols].
// ---------------------------------------------------------------------------
__global__ __launch_bounds__(64)
void prep_kernel(const float* __restrict__ Wq, const float* __restrict__ bq,
                 const float* __restrict__ Wk, const float* __restrict__ bk,
                 const float* __restrict__ Wv, const float* __restrict__ bv,
                 unsigned short* __restrict__ Wq_t, unsigned short* __restrict__ Wkv_t,
                 float* __restrict__ bq_s, float* __restrict__ bkv)
{
    const int n = blockIdx.x;
    const int lane = threadIdx.x;
    if (n == 192) {
        bq_s[lane]   = bq[lane] * 0.125f;
        bkv[lane]    = bk[lane];
        bkv[64+lane] = bv[lane];
        return;
    }
    const int d0 = lane * 8;
    unsigned short t[8];
    if (n < 64) {
        #pragma unroll
        for (int j = 0; j < 8; ++j) t[j] = f2bf(Wq[(size_t)(d0+j)*F_ + n] * 0.125f);
        *(uint4*)&Wq_t[(size_t)n*D_ + d0] = make_uint4(
            (unsigned)t[0]|((unsigned)t[1]<<16), (unsigned)t[2]|((unsigned)t[3]<<16),
            (unsigned)t[4]|((unsigned)t[5]<<16), (unsigned)t[6]|((unsigned)t[7]<<16));
    } else {
        const int nn  = n - 64;
        const float* W = (nn < 64) ? Wk : Wv;
        const int col = nn & 63;
        #pragma unroll
        for (int j = 0; j < 8; ++j) t[j] = f2bf(W[(size_t)(d0+j)*F_ + col]);
        *(uint4*)&Wkv_t[(size_t)nn*D_ + d0] = make_uint4(
            (unsigned)t[0]|((unsigned)t[1]<<16), (unsigned)t[2]|((unsigned)t[3]<<16),
            (unsigned)t[4]|((unsigned)t[5]<<16), (unsigned)t[6]|((unsigned)t[7]<<16));
    }
}

// ---------------------------------------------------------------------------
// MFMA projection GEMM. MODE 0: q=target@Wq_t -> bf16 (scaled). MODE 1: node
// -> nk bf16 + node_v f32. MODE 2: leaf -> lk bf16 + V^T bf16 (LDS transpose)
// + agg logits. Block = 64 rows, 4 waves x 16-row m-subtiles, N = 64 or 128.
// Fragment conventions identical to the verified attn kernel.
// ---------------------------------------------------------------------------
template<int MODE>
__global__ __launch_bounds__(256, 2)
void proj_gemm(const float* __restrict__ X,
               const unsigned short* __restrict__ Wt,
               const float* __restrict__ bias,
               const float* __restrict__ Wagg,
               const float* __restrict__ bagg,
               unsigned short* __restrict__ outK,
               float* __restrict__ outVf,
               unsigned short* __restrict__ outVt,
               float* __restrict__ outAgg)
{
    constexpr int NT = (MODE == 0) ? 4 : 8;
    __shared__ unsigned short Xs[64 * XSTR];                    // 65 KB
    __shared__ unsigned short Vt_lds[(MODE == 2) ? (64*72) : 4]; // 9 KB leaf

    const int tid = threadIdx.x;
    const int r0  = blockIdx.x * 64;

    // stage 64x512 f32 -> bf16 LDS
    const float4* xsrc = (const float4*)(X + (size_t)r0 * D_);
    #pragma unroll 4
    for (int j = 0; j < 32; ++j) {
        const int s = tid + j * 256;             // float4 slot; 128 per row
        const float4 v = xsrc[s];
        *(uint2*)&Xs[(s >> 7)*XSTR + (s & 127)*4] =
            make_uint2(pack_bf(v.x, v.y), pack_bf(v.z, v.w));
    }
    __syncthreads();

    const int w = tid >> 6, l = tid & 63, c = l & 15, h = l >> 4;
    float bias_c[NT];
    #pragma unroll
    for (int s2 = 0; s2 < NT; ++s2) bias_c[s2] = bias[16*s2 + c];

    f32x4 acc[NT];
    #pragma unroll
    for (int s2 = 0; s2 < NT; ++s2) acc[s2] = (f32x4){0,0,0,0};

    const unsigned short* arow = &Xs[(16*w + c) * XSTR];
    #pragma unroll
    for (int kk = 0; kk < 16; ++kk) {
        const short8 af = *(const short8*)(arow + kk*32 + 8*h);   // A[row=c][k]
        #pragma unroll
        for (int s2 = 0; s2 < NT; ++s2) {
            const short8 bfr = *(const short8*)(Wt + (size_t)(16*s2 + c)*D_ + kk*32 + 8*h);
            acc[s2] = __builtin_amdgcn_mfma_f32_16x16x32_bf16(af, bfr, acc[s2], 0,0,0);
        }
    }

    // K/q outputs: C[m=16w+4h+r][n=16s2+c]
    #pragma unroll
    for (int s2 = 0; s2 < 4; ++s2) {
        #pragma unroll
        for (int r = 0; r < 4; ++r) {
            const int m = 16*w + 4*h + r;
            outK[(size_t)(r0 + m)*F_ + 16*s2 + c] = f2bf(acc[s2][r] + bias_c[s2]);
        }
    }
    if constexpr (MODE == 1) {
        #pragma unroll
        for (int s2 = 4; s2 < 8; ++s2) {
            #pragma unroll
            for (int r = 0; r < 4; ++r) {
                const int m = 16*w + 4*h + r;
                outVf[(size_t)(r0 + m)*F_ + 16*(s2-4) + c] = acc[s2][r] + bias_c[s2];
            }
        }
    }
    if constexpr (MODE == 2) {
        // V -> LDS transpose [f][m]
        #pragma unroll
        for (int s2 = 4; s2 < 8; ++s2) {
            #pragma unroll
            for (int r = 0; r < 4; ++r)
                Vt_lds[(16*(s2-4) + c)*72 + 16*w + 4*h + r] = f2bf(acc[s2][r] + bias_c[s2]);
        }
        // agg logit per leaf row from bf16 Xs
        {
            const int row = tid >> 2, qd = tid & 3;
            const unsigned short* xr = &Xs[row*XSTR + qd*128];
            const float* wr = Wagg + qd*128;
            float p = 0.f;
            #pragma unroll
            for (int j = 0; j < 16; ++j) {
                const short8 xv = *(const short8*)(xr + j*8);
                const float4 wa0 = *(const float4*)(wr + j*8);
                const float4 wa1 = *(const float4*)(wr + j*8 + 4);
                p += bf2f(xv[0])*wa0.x + bf2f(xv[1])*wa0.y
                   + bf2f(xv[2])*wa0.z + bf2f(xv[3])*wa0.w
                   + bf2f(xv[4])*wa1.x + bf2f(xv[5])*wa1.y
                   + bf2f(xv[6])*wa1.z + bf2f(xv[7])*wa1.w;
            }
            p += __shfl_xor(p, 1);
            p += __shfl_xor(p, 2);
            if (qd == 0) outAgg[r0 + row] = p + bagg[0];
        }
        __syncthreads();
        // coalesced V^T writeout: thread -> (f, 16-leaf segment)
        {
            const int f = tid >> 2, seg = tid & 3;
            const int b = r0 >> 12, l0 = r0 & (L_ - 1);
            const uint4 a0 = *(const uint4*)&Vt_lds[f*72 + seg*16];
            const uint4 a1 = *(const uint4*)&Vt_lds[f*72 + seg*16 + 8];
            unsigned short* dst = outVt + ((size_t)(b*F_ + f))*L_ + l0 + seg*16;
            *(uint4*)dst = a0;
            *(uint4*)(dst + 8) = a1;
        }
    }
}

// ---------------------------------------------------------------------------
// Suffix scan over node groups; now also builds the group interp sums G from
// lvt (contiguous bf16) + node_v + root. One wave per (b,f).
// ---------------------------------------------------------------------------
__global__ __launch_bounds__(256)
void scan_kernel(const unsigned short* __restrict__ lvt,
                 const float* __restrict__ node_v,
                 const float* __restrict__ root,
                 float* __restrict__ Tnext)
{
    const int gtid = blockIdx.x * 256 + threadIdx.x;
    const int wv   = gtid >> 6;
    const int lane = threadIdx.x & 63;
    const int b = wv >> 6;
    const int f = wv & 63;

    const unsigned short* vt = lvt + ((size_t)(b*F_ + f))*L_ + lane*64;
    const float rootf = root[b*F_ + f];
    float gv[8];
    #pragma unroll
    for (int g = 0; g < 8; ++g) {
        const short8 xv = *(const short8*)(vt + g*8);
        const float s8 = bf2f(xv[0])+bf2f(xv[1])+bf2f(xv[2])+bf2f(xv[3])
                       + bf2f(xv[4])+bf2f(xv[5])+bf2f(xv[6])+bf2f(xv[7]);
        const float nv = node_v[((size_t)(b*N_ + lane*8 + g))*F_ + f];
        gv[g] = (s8 + 8.f*(rootf + nv)) * (1.f/3.f);
    }

    float s[9];
    s[8] = 0.f;
    #pragma unroll
    for (int j = 7; j >= 0; --j) s[j] = s[j+1] + gv[j];

    float x = s[0];
    const float lsum = x;
    #pragma unroll
    for (int off = 1; off < 64; off <<= 1) {
        float t = __shfl_down(x, off);
        if (lane + off < 64) x += t;
    }
    const float excl = x - lsum;

    float* outp = Tnext + ((size_t)(b*N_ + lane*8))*F_ + f;
    #pragma unroll
    for (int j = 0; j < 8; ++j) outp[(size_t)j*F_] = excl + s[j+1];
}

// ---------------------------------------------------------------------------
// node_hat -> transposed bf16 [B][F][N]; leaf values from lvt (bf16).
// ---------------------------------------------------------------------------
__global__ __launch_bounds__(64)
void node_hat_kernel(const float* __restrict__ Tnext, const float* __restrict__ agg,
                     const unsigned short* __restrict__ lvt, const float* __restrict__ node_v,
                     const float* __restrict__ root, unsigned short* __restrict__ nh_t)
{
    const int bn = blockIdx.x;
    const int b = bn >> 9;
    const int n = bn & (N_ - 1);
    const int f = threadIdx.x;

    float a[8];
    #pragma unroll
    for (int c = 0; c < 8; ++c) a[c] = agg[(size_t)b*L_ + n*8 + c];
    float mx = a[0];
    #pragma unroll
    for (int c = 1; c < 8; ++c) mx = fmaxf(mx, a[c]);
    float wgt[8]; float wsum = 0.f;
    #pragma unroll
    for (int c = 0; c < 8; ++c) { wgt[c] = __expf(a[c] - mx); wsum += wgt[c]; }

    const float tn    = Tnext[(size_t)bn*F_ + f];
    const float rootf = root[b*F_ + f];
    const float nv    = node_v[(size_t)bn*F_ + f];
    const short8 lv8  = *(const short8*)(lvt + ((size_t)(b*F_ + f))*L_ + n*8);
    float run = 0.f, acc = 0.f;
    #pragma unroll
    for (int c = 7; c >= 0; --c) {
        const int l = n*8 + c;
        const float interp = (rootf + nv + bf2f(lv8[c])) * (1.f/3.f);
        run += interp;
        const float up = (tn + run) / (float)(L_ - l);
        acc = fmaf(wgt[c], up, acc);
    }
    nh_t[((size_t)(b*F_ + f))*N_ + n] = f2bf(acc / wsum);
}

// ---------------------------------------------------------------------------
// MFMA dual-softmax attention, transpose-free (verified round 4, unchanged).
// ---------------------------------------------------------------------------
__global__ __launch_bounds__(256, 2)
void attn_kernel(const unsigned short* __restrict__ qb,
                 const unsigned short* __restrict__ nk,
                 const unsigned short* __restrict__ nht,
                 const unsigned short* __restrict__ lk,
                 const unsigned short* __restrict__ lvt,
                 float* __restrict__ pacc, float* __restrict__ pd)
{
    __shared__ unsigned short Ks[2][64*KSTR];   // 18 KB
    __shared__ unsigned short Vt[2][64*KSTR];   // 18 KB

    const int wg  = (blockIdx.x & 7) * 64 + (blockIdx.x >> 3);
    const int b   = wg >> 6;
    const int sl  = (wg >> 4) & 3;
    const int t0  = (wg & 15) * 64;

    const int tid = threadIdx.x;
    const int w   = tid >> 6;
    const int l   = tid & 63;
    const int c   = l & 15;
    const int h   = l >> 4;
    const int sm  = tid >> 2;      // staging row
    const int sc  = tid & 3;       // staging 16-col chunk

    const unsigned short* qrow = qb + ((size_t)(b*T_ + t0 + w*16 + c))*F_ + 8*h;
    const short8 qf0 = *(const short8*)qrow;
    const short8 qf1 = *(const short8*)(qrow + 32);

    f32x4 accN[4] = {{0,0,0,0},{0,0,0,0},{0,0,0,0},{0,0,0,0}};
    f32x4 accL[4] = {{0,0,0,0},{0,0,0,0},{0,0,0,0},{0,0,0,0}};
    float dsN = 0.f, dsL = 0.f;

    const unsigned short* Knb = nk  + (size_t)b*N_*F_;
    const unsigned short* Klb = lk  + (size_t)b*L_*F_;
    const unsigned short* Vnb = nht + (size_t)b*F_*N_;   // [F][N]
    const unsigned short* Vlb = lvt + (size_t)b*F_*L_;   // [F][L]

    const int ti0 = sl * TPS;

    uint4 sk0, sk1, sv0, sv1;
    auto load_tile = [&](int ti) {
        if (ti < 8) {
            const unsigned short* Kb = Knb + (size_t)ti*64*F_;
            sk0 = *(const uint4*)(Kb + sm*64 + sc*16);
            sk1 = *(const uint4*)(Kb + sm*64 + sc*16 + 8);
            const unsigned short* Vb = Vnb + (size_t)sm*N_ + ti*64;
            sv0 = *(const uint4*)(Vb + sc*16);
            sv1 = *(const uint4*)(Vb + sc*16 + 8);
        } else {
            const unsigned short* Kb = Klb + (size_t)(ti-8)*64*F_;
            sk0 = *(const uint4*)(Kb + sm*64 + sc*16);
            sk1 = *(const uint4*)(Kb + sm*64 + sc*16 + 8);
            const unsigned short* Vb = Vlb + (size_t)sm*L_ + (ti-8)*64;
            sv0 = *(const uint4*)(Vb + sc*16);
            sv1 = *(const uint4*)(Vb + sc*16 + 8);
        }
    };
    auto write_tile = [&](int pb) {
        *(uint4*)&Ks[pb][sm*KSTR + sc*16]     = sk0;
        *(uint4*)&Ks[pb][sm*KSTR + sc*16 + 8] = sk1;
        *(uint4*)&Vt[pb][sm*KSTR + sc*16]     = sv0;
        *(uint4*)&Vt[pb][sm*KSTR + sc*16 + 8] = sv1;
    };

    load_tile(ti0);
    write_tile(0);
    __syncthreads();

    const int srcA = c + 16*((2*h) & 3);
    const int srcB = c + 16*((2*h + 1) & 3);
    const int hs   = h >> 1;

    for (int i = 0; i < TPS; ++i) {
        const int  ti  = ti0 + i;
        const bool isN = ti < 8;
        const int  pb  = i & 1;
        const bool nxt = (i + 1 < TPS);
        if (nxt) load_tile(ti + 1);

        f32x4 st[4] = {{0,0,0,0},{0,0,0,0},{0,0,0,0},{0,0,0,0}};
        #pragma unroll
        for (int ss = 0; ss < 4; ++ss) {
            const short8 kf0 = *(const short8*)&Ks[pb][(16*ss + c)*KSTR + 8*h];
            st[ss] = __builtin_amdgcn_mfma_f32_16x16x32_bf16(kf0, qf0, st[ss], 0,0,0);
            const short8 kf1 = *(const short8*)&Ks[pb][(16*ss + c)*KSTR + 32 + 8*h];
            st[ss] = __builtin_amdgcn_mfma_f32_16x16x32_bf16(kf1, qf1, st[ss], 0,0,0);
        }

        unsigned pk0[4], pk1[4];
        float psum = 0.f;
        #pragma unroll
        for (int ss = 0; ss < 4; ++ss) {
            #pragma unroll
            for (int r = 0; r < 4; ++r) { st[ss][r] = __expf(st[ss][r]); psum += st[ss][r]; }
            pk0[ss] = pack_bf(st[ss][0], st[ss][1]);
            pk1[ss] = pack_bf(st[ss][2], st[ss][3]);
        }
        if (isN) dsN += psum; else dsL += psum;

        #pragma unroll
        for (int k00 = 0; k00 < 2; ++k00) {
            const unsigned d0a = __shfl(pk0[2*k00+0], srcA);
            const unsigned d0b = __shfl(pk0[2*k00+1], srcA);
            const unsigned d1a = __shfl(pk1[2*k00+0], srcA);
            const unsigned d1b = __shfl(pk1[2*k00+1], srcA);
            const unsigned d2a = __shfl(pk0[2*k00+0], srcB);
            const unsigned d2b = __shfl(pk0[2*k00+1], srcB);
            const unsigned d3a = __shfl(pk1[2*k00+0], srcB);
            const unsigned d3b = __shfl(pk1[2*k00+1], srcB);
            const short8 bp = frag_from4(hs ? d0b : d0a, hs ? d1b : d1a,
                                         hs ? d2b : d2a, hs ? d3b : d3a);
            if (isN) {
                #pragma unroll
                for (int s2 = 0; s2 < 4; ++s2) {
                    const short8 af = *(const short8*)&Vt[pb][(16*s2 + c)*KSTR + 32*k00 + 8*h];
                    accN[s2] = __builtin_amdgcn_mfma_f32_16x16x32_bf16(af, bp, accN[s2], 0,0,0);
                }
            } else {
                #pragma unroll
                for (int s2 = 0; s2 < 4; ++s2) {
                    const short8 af = *(const short8*)&Vt[pb][(16*s2 + c)*KSTR + 32*k00 + 8*h];
                    accL[s2] = __builtin_amdgcn_mfma_f32_16x16x32_bf16(af, bp, accL[s2], 0,0,0);
                }
            }
        }

        if (nxt) {
            write_tile(pb ^ 1);
            __syncthreads();
        }
    }

    dsN += __shfl_xor(dsN, 16);  dsN += __shfl_xor(dsN, 32);
    dsL += __shfl_xor(dsL, 16);  dsL += __shfl_xor(dsL, 32);

    const int gt = b*T_ + t0 + w*16 + c;
    float* baseN = pacc + (((size_t)sl*(B_*T_) + gt)*2 + 0)*F_;
    float* baseL = baseN + F_;
    #pragma unroll
    for (int s2 = 0; s2 < 4; ++s2) {
        #pragma unroll
        for (int r = 0; r < 4; ++r) {
            baseN[s2*16 + 4*h + r] = accN[s2][r];
            baseL[s2*16 + 4*h + r] = accL[s2][r];
        }
    }
    if (h == 0) {
        pd[((size_t)sl*(B_*T_) + gt)*2 + 0] = dsN;
        pd[((size_t)sl*(B_*T_) + gt)*2 + 1] = dsL;
    }
}

// ---------------------------------------------------------------------------
// Combine slices + final feature softmax. One wave per target, lane = f.
// ---------------------------------------------------------------------------
__global__ __launch_bounds__(256)
void combine_kernel(const float* __restrict__ pacc, const float* __restrict__ pd,
                    float* __restrict__ out)
{
    const int gt = (blockIdx.x * 256 + threadIdx.x) >> 6;
    const int f  = threadIdx.x & 63;

    float aN = 0.f, aL = 0.f, dN = 0.f, dL = 0.f;
    #pragma unroll
    for (int s = 0; s < SLICES; ++s) {
        const size_t base = ((size_t)s*(B_*T_) + gt)*2;
        aN += pacc[(base + 0)*F_ + f];
        aL += pacc[(base + 1)*F_ + f];
        dN += pd[base + 0];
        dL += pd[base + 1];
    }
    float lg = aN / dN + aL / dL;
    float mx = lg;
    #pragma unroll
    for (int off = 1; off < 64; off <<= 1) mx = fmaxf(mx, __shfl_xor(mx, off));
    const float e = __expf(lg - mx);
    float ssum = e;
    #pragma unroll
    for (int off = 1; off < 64; off <<= 1) ssum += __shfl_xor(ssum, off);
    out[(size_t)gt*F_ + f] = e / ssum;
}

// ---------------------------------------------------------------------------
extern "C" void kernel_launch(void* const* d_in, const int* in_sizes, int n_in,
                              void* d_out, int out_size, void* d_ws, size_t ws_size,
                              hipStream_t stream)
{
    const float* root   = (const float*)d_in[0];
    const float* node   = (const float*)d_in[1];
    const float* leaf   = (const float*)d_in[2];
    const float* target = (const float*)d_in[3];
    const float* Wq   = (const float*)d_in[4];
    const float* bq   = (const float*)d_in[5];
    const float* Wk   = (const float*)d_in[6];
    const float* bk   = (const float*)d_in[7];
    const float* Wv   = (const float*)d_in[8];
    const float* bv   = (const float*)d_in[9];
    const float* Wagg = (const float*)d_in[10];
    const float* bagg = (const float*)d_in[11];
    float* out = (float*)d_out;

    // workspace layout (bytes), ~29.7 MB
    char* wp = (char*)d_ws;
    unsigned short* q_bf  = (unsigned short*)wp; wp += (size_t)B_*T_*F_*2;   // 1 MB
    unsigned short* nk_bf = (unsigned short*)wp; wp += (size_t)B_*N_*F_*2;   // 0.5 MB
    unsigned short* lk_bf = (unsigned short*)wp; wp += (size_t)B_*L_*F_*2;   // 4 MB
    unsigned short* lvt   = (unsigned short*)wp; wp += (size_t)B_*F_*L_*2;   // 4 MB
    unsigned short* nht   = (unsigned short*)wp; wp += (size_t)B_*F_*N_*2;   // 0.5 MB
    unsigned short* Wq_t  = (unsigned short*)wp; wp += (size_t)64*D_*2;      // 64 KB
    unsigned short* Wkv_t = (unsigned short*)wp; wp += (size_t)128*D_*2;     // 128 KB
    float* node_v = (float*)wp; wp += (size_t)B_*N_*F_*4;                    // 1 MB
    float* agg    = (float*)wp; wp += (size_t)B_*L_*4;                       // 128 KB
    float* Tnext  = (float*)wp; wp += (size_t)B_*N_*F_*4;                    // 1 MB
    float* bq_s   = (float*)wp; wp += 512;
    float* bkv    = (float*)wp; wp += 512;
    float* pacc   = (float*)wp; wp += (size_t)SLICES*B_*T_*2*F_*4;           // 16 MB
    float* pd     = (float*)wp;                                              // 256 KB

    prep_kernel<<<193, 64, 0, stream>>>(Wq, bq, Wk, bk, Wv, bv, Wq_t, Wkv_t, bq_s, bkv);
    proj_gemm<0><<<(B_*T_)/64, 256, 0, stream>>>(target, Wq_t, bq_s,
        nullptr, nullptr, q_bf, nullptr, nullptr, nullptr);
    proj_gemm<1><<<(B_*N_)/64, 256, 0, stream>>>(node, Wkv_t, bkv,
        nullptr, nullptr, nk_bf, node_v, nullptr, nullptr);
    proj_gemm<2><<<(B_*L_)/64, 256, 0, stream>>>(leaf, Wkv_t, bkv,
        Wagg, bagg, lk_bf, nullptr, lvt, agg);
    scan_kernel<<<128, 256, 0, stream>>>(lvt, node_v, root, Tnext);
    node_hat_kernel<<<B_*N_, 64, 0, stream>>>(Tnext, agg, lvt, node_v, root, nht);
    attn_kernel<<<B_*(T_/64)*SLICES, 256, 0, stream>>>(q_bf, nk_bf, nht, lk_bf, lvt, pacc, pd);
    combine_kernel<<<(B_*T_)/4, 256, 0, stream>>>(pacc, pd, out);
}

// Round 6
// 99.681 us; speedup vs baseline: 7.1017x; 1.3638x over previous
//
#include <hip/hip_runtime.h>

// DecoderAttention: B=8, T=1024, N=512, L=4096, D=512, F=64, BR=8
#define B_ 8
#define T_ 1024
#define N_ 512
#define L_ 4096
#define D_ 512
#define F_ 64
#define SLICES 4
#define TPS 18    // tiles per slice (72 total: 8 node + 64 leaf)
#define KSTR 72   // attn LDS row stride (bf16) for K / V^T tiles
#define XSTR 520  // proj LDS row stride (bf16)

typedef __attribute__((ext_vector_type(8))) short short8;
typedef __attribute__((ext_vector_type(4))) float f32x4;

__device__ __forceinline__ unsigned short f2bf(float x){
    unsigned u = __builtin_bit_cast(unsigned, x);
    u += 0x7FFFu + ((u >> 16) & 1u);           // RNE
    return (unsigned short)(u >> 16);
}
__device__ __forceinline__ unsigned pack_bf(float lo, float hi){
    return (unsigned)f2bf(lo) | ((unsigned)f2bf(hi) << 16);
}
__device__ __forceinline__ float bf2f(short s){
    return __builtin_bit_cast(float, ((unsigned)(unsigned short)s) << 16);
}
__device__ __forceinline__ short8 frag_from4(unsigned d0, unsigned d1, unsigned d2, unsigned d3){
    union { unsigned u[4]; short8 s; } t;
    t.u[0] = d0; t.u[1] = d1; t.u[2] = d2; t.u[3] = d3;
    return t.s;
}

// ---------------------------------------------------------------------------
// Weight prep: transposed bf16 weights + bias vectors.
// ---------------------------------------------------------------------------
__global__ __launch_bounds__(64)
void prep_kernel(const float* __restrict__ Wq, const float* __restrict__ bq,
                 const float* __restrict__ Wk, const float* __restrict__ bk,
                 const float* __restrict__ Wv, const float* __restrict__ bv,
                 unsigned short* __restrict__ Wq_t, unsigned short* __restrict__ Wkv_t,
                 float* __restrict__ bq_s, float* __restrict__ bkv)
{
    const int n = blockIdx.x;
    const int lane = threadIdx.x;
    if (n == 192) {
        bq_s[lane]   = bq[lane] * 0.125f;
        bkv[lane]    = bk[lane];
        bkv[64+lane] = bv[lane];
        return;
    }
    const int d0 = lane * 8;
    unsigned short t[8];
    if (n < 64) {
        #pragma unroll
        for (int j = 0; j < 8; ++j) t[j] = f2bf(Wq[(size_t)(d0+j)*F_ + n] * 0.125f);
        *(uint4*)&Wq_t[(size_t)n*D_ + d0] = make_uint4(
            (unsigned)t[0]|((unsigned)t[1]<<16), (unsigned)t[2]|((unsigned)t[3]<<16),
            (unsigned)t[4]|((unsigned)t[5]<<16), (unsigned)t[6]|((unsigned)t[7]<<16));
    } else {
        const int nn  = n - 64;
        const float* W = (nn < 64) ? Wk : Wv;
        const int col = nn & 63;
        #pragma unroll
        for (int j = 0; j < 8; ++j) t[j] = f2bf(W[(size_t)(d0+j)*F_ + col]);
        *(uint4*)&Wkv_t[(size_t)nn*D_ + d0] = make_uint4(
            (unsigned)t[0]|((unsigned)t[1]<<16), (unsigned)t[2]|((unsigned)t[3]<<16),
            (unsigned)t[4]|((unsigned)t[5]<<16), (unsigned)t[6]|((unsigned)t[7]<<16));
    }
}

// ---------------------------------------------------------------------------
// MFMA projection GEMM, weights-in-registers.
// Wave w owns NPW n-tiles (cols 16*NPW*w ..) x ALL 4 m-subtiles; its B-frags
// (NPW*16, 16B each) are preloaded to VGPRs before staging, so the kk-loop
// is pure ds_read + MFMA (no global latency exposed).
// MODE 0: q (NPW=1). MODE 1: node k+v (NPW=2). MODE 2: leaf (NPW=2, +V^T
// via LDS transpose, +agg logits).
// ---------------------------------------------------------------------------
template<int MODE>
__global__ __launch_bounds__(256, 2)
void proj_gemm(const float* __restrict__ X,
               const unsigned short* __restrict__ Wt,
               const float* __restrict__ bias,
               const float* __restrict__ Wagg,
               const float* __restrict__ bagg,
               unsigned short* __restrict__ outK,
               float* __restrict__ outVf,
               unsigned short* __restrict__ outVt,
               float* __restrict__ outAgg)
{
    constexpr int NPW = (MODE == 0) ? 1 : 2;
    __shared__ unsigned short Xs[64 * XSTR];                     // 65 KB
    __shared__ unsigned short Vt_lds[(MODE == 2) ? (64*72) : 4]; // 9 KB leaf

    const int tid = threadIdx.x;
    const int r0  = blockIdx.x * 64;
    const int w = tid >> 6, l = tid & 63, c = l & 15, h = l >> 4;

    // ---- B-frag preload (issued first; latency hides under staging) ----
    short8 breg[NPW][16];
    #pragma unroll
    for (int p = 0; p < NPW; ++p) {
        const unsigned short* wrow = Wt + (size_t)(16*(NPW*w + p) + c)*D_ + 8*h;
        #pragma unroll
        for (int kk = 0; kk < 16; ++kk)
            breg[p][kk] = *(const short8*)(wrow + kk*32);
    }

    // ---- stage 64x512 f32 -> bf16 LDS ----
    const float4* xsrc = (const float4*)(X + (size_t)r0 * D_);
    #pragma unroll 4
    for (int j = 0; j < 32; ++j) {
        const int s = tid + j * 256;             // float4 slot; 128 per row
        const float4 v = xsrc[s];
        *(uint2*)&Xs[(s >> 7)*XSTR + (s & 127)*4] =
            make_uint2(pack_bf(v.x, v.y), pack_bf(v.z, v.w));
    }
    __syncthreads();

    // ---- kk loop: 4 ds_read (A per m-subtile) + NPW*4 MFMA per step ----
    f32x4 acc[NPW][4];
    #pragma unroll
    for (int p = 0; p < NPW; ++p)
        #pragma unroll
        for (int m = 0; m < 4; ++m) acc[p][m] = (f32x4){0,0,0,0};

    #pragma unroll
    for (int kk = 0; kk < 16; ++kk) {
        #pragma unroll
        for (int m = 0; m < 4; ++m) {
            const short8 af = *(const short8*)&Xs[(16*m + c)*XSTR + kk*32 + 8*h];
            #pragma unroll
            for (int p = 0; p < NPW; ++p)
                acc[p][m] = __builtin_amdgcn_mfma_f32_16x16x32_bf16(af, breg[p][kk], acc[p][m], 0,0,0);
        }
    }

    // ---- epilogues ----
    #pragma unroll
    for (int p = 0; p < NPW; ++p) {
        const int s2g = NPW*w + p;
        const float bc = bias[16*s2g + c];
        if (MODE == 0 || s2g < 4) {
            // K / q columns
            #pragma unroll
            for (int m = 0; m < 4; ++m)
                #pragma unroll
                for (int r = 0; r < 4; ++r)
                    outK[(size_t)(r0 + 16*m + 4*h + r)*F_ + 16*s2g + c] = f2bf(acc[p][m][r] + bc);
        } else if (MODE == 1) {
            #pragma unroll
            for (int m = 0; m < 4; ++m)
                #pragma unroll
                for (int r = 0; r < 4; ++r)
                    outVf[(size_t)(r0 + 16*m + 4*h + r)*F_ + 16*(s2g-4) + c] = acc[p][m][r] + bc;
        } else {
            // MODE 2: V -> LDS transpose [f][m]
            #pragma unroll
            for (int m = 0; m < 4; ++m)
                #pragma unroll
                for (int r = 0; r < 4; ++r)
                    Vt_lds[(16*(s2g-4) + c)*72 + 16*m + 4*h + r] = f2bf(acc[p][m][r] + bc);
        }
    }

    if constexpr (MODE == 2) {
        // agg logit per leaf row from bf16 Xs
        {
            const int row = tid >> 2, qd = tid & 3;
            const unsigned short* xr = &Xs[row*XSTR + qd*128];
            const float* wr = Wagg + qd*128;
            float p = 0.f;
            #pragma unroll
            for (int j = 0; j < 16; ++j) {
                const short8 xv = *(const short8*)(xr + j*8);
                const float4 wa0 = *(const float4*)(wr + j*8);
                const float4 wa1 = *(const float4*)(wr + j*8 + 4);
                p += bf2f(xv[0])*wa0.x + bf2f(xv[1])*wa0.y
                   + bf2f(xv[2])*wa0.z + bf2f(xv[3])*wa0.w
                   + bf2f(xv[4])*wa1.x + bf2f(xv[5])*wa1.y
                   + bf2f(xv[6])*wa1.z + bf2f(xv[7])*wa1.w;
            }
            p += __shfl_xor(p, 1);
            p += __shfl_xor(p, 2);
            if (qd == 0) outAgg[r0 + row] = p + bagg[0];
        }
        __syncthreads();
        // coalesced V^T writeout: thread -> (f, 16-leaf segment)
        {
            const int f = tid >> 2, seg = tid & 3;
            const int b = r0 >> 12, l0 = r0 & (L_ - 1);
            const uint4 a0 = *(const uint4*)&Vt_lds[f*72 + seg*16];
            const uint4 a1 = *(const uint4*)&Vt_lds[f*72 + seg*16 + 8];
            unsigned short* dst = outVt + ((size_t)(b*F_ + f))*L_ + l0 + seg*16;
            *(uint4*)dst = a0;
            *(uint4*)(dst + 8) = a1;
        }
    }
}

// ---------------------------------------------------------------------------
// Suffix scan over node groups; builds group interp sums G from lvt.
// ---------------------------------------------------------------------------
__global__ __launch_bounds__(256)
void scan_kernel(const unsigned short* __restrict__ lvt,
                 const float* __restrict__ node_v,
                 const float* __restrict__ root,
                 float* __restrict__ Tnext)
{
    const int gtid = blockIdx.x * 256 + threadIdx.x;
    const int wv   = gtid >> 6;
    const int lane = threadIdx.x & 63;
    const int b = wv >> 6;
    const int f = wv & 63;

    const unsigned short* vt = lvt + ((size_t)(b*F_ + f))*L_ + lane*64;
    const float rootf = root[b*F_ + f];
    float gv[8];
    #pragma unroll
    for (int g = 0; g < 8; ++g) {
        const short8 xv = *(const short8*)(vt + g*8);
        const float s8 = bf2f(xv[0])+bf2f(xv[1])+bf2f(xv[2])+bf2f(xv[3])
                       + bf2f(xv[4])+bf2f(xv[5])+bf2f(xv[6])+bf2f(xv[7]);
        const float nv = node_v[((size_t)(b*N_ + lane*8 + g))*F_ + f];
        gv[g] = (s8 + 8.f*(rootf + nv)) * (1.f/3.f);
    }

    float s[9];
    s[8] = 0.f;
    #pragma unroll
    for (int j = 7; j >= 0; --j) s[j] = s[j+1] + gv[j];

    float x = s[0];
    const float lsum = x;
    #pragma unroll
    for (int off = 1; off < 64; off <<= 1) {
        float t = __shfl_down(x, off);
        if (lane + off < 64) x += t;
    }
    const float excl = x - lsum;

    float* outp = Tnext + ((size_t)(b*N_ + lane*8))*F_ + f;
    #pragma unroll
    for (int j = 0; j < 8; ++j) outp[(size_t)j*F_] = excl + s[j+1];
}

// ---------------------------------------------------------------------------
// node_hat -> transposed bf16 [B][F][N].
// ---------------------------------------------------------------------------
__global__ __launch_bounds__(64)
void node_hat_kernel(const float* __restrict__ Tnext, const float* __restrict__ agg,
                     const unsigned short* __restrict__ lvt, const float* __restrict__ node_v,
                     const float* __restrict__ root, unsigned short* __restrict__ nh_t)
{
    const int bn = blockIdx.x;
    const int b = bn >> 9;
    const int n = bn & (N_ - 1);
    const int f = threadIdx.x;

    float a[8];
    #pragma unroll
    for (int c = 0; c < 8; ++c) a[c] = agg[(size_t)b*L_ + n*8 + c];
    float mx = a[0];
    #pragma unroll
    for (int c = 1; c < 8; ++c) mx = fmaxf(mx, a[c]);
    float wgt[8]; float wsum = 0.f;
    #pragma unroll
    for (int c = 0; c < 8; ++c) { wgt[c] = __expf(a[c] - mx); wsum += wgt[c]; }

    const float tn    = Tnext[(size_t)bn*F_ + f];
    const float rootf = root[b*F_ + f];
    const float nv    = node_v[(size_t)bn*F_ + f];
    const short8 lv8  = *(const short8*)(lvt + ((size_t)(b*F_ + f))*L_ + n*8);
    float run = 0.f, acc = 0.f;
    #pragma unroll
    for (int c = 7; c >= 0; --c) {
        const int l = n*8 + c;
        const float interp = (rootf + nv + bf2f(lv8[c])) * (1.f/3.f);
        run += interp;
        const float up = (tn + run) / (float)(L_ - l);
        acc = fmaf(wgt[c], up, acc);
    }
    nh_t[((size_t)(b*F_ + f))*N_ + n] = f2bf(acc / wsum);
}

// ---------------------------------------------------------------------------
// MFMA dual-softmax attention, transpose-free (verified round 4, unchanged).
// ---------------------------------------------------------------------------
__global__ __launch_bounds__(256, 2)
void attn_kernel(const unsigned short* __restrict__ qb,
                 const unsigned short* __restrict__ nk,
                 const unsigned short* __restrict__ nht,
                 const unsigned short* __restrict__ lk,
                 const unsigned short* __restrict__ lvt,
                 float* __restrict__ pacc, float* __restrict__ pd)
{
    __shared__ unsigned short Ks[2][64*KSTR];   // 18 KB
    __shared__ unsigned short Vt[2][64*KSTR];   // 18 KB

    const int wg  = (blockIdx.x & 7) * 64 + (blockIdx.x >> 3);
    const int b   = wg >> 6;
    const int sl  = (wg >> 4) & 3;
    const int t0  = (wg & 15) * 64;

    const int tid = threadIdx.x;
    const int w   = tid >> 6;
    const int l   = tid & 63;
    const int c   = l & 15;
    const int h   = l >> 4;
    const int sm  = tid >> 2;      // staging row
    const int sc  = tid & 3;       // staging 16-col chunk

    const unsigned short* qrow = qb + ((size_t)(b*T_ + t0 + w*16 + c))*F_ + 8*h;
    const short8 qf0 = *(const short8*)qrow;
    const short8 qf1 = *(const short8*)(qrow + 32);

    f32x4 accN[4] = {{0,0,0,0},{0,0,0,0},{0,0,0,0},{0,0,0,0}};
    f32x4 accL[4] = {{0,0,0,0},{0,0,0,0},{0,0,0,0},{0,0,0,0}};
    float dsN = 0.f, dsL = 0.f;

    const unsigned short* Knb = nk  + (size_t)b*N_*F_;
    const unsigned short* Klb = lk  + (size_t)b*L_*F_;
    const unsigned short* Vnb = nht + (size_t)b*F_*N_;   // [F][N]
    const unsigned short* Vlb = lvt + (size_t)b*F_*L_;   // [F][L]

    const int ti0 = sl * TPS;

    uint4 sk0, sk1, sv0, sv1;
    auto load_tile = [&](int ti) {
        if (ti < 8) {
            const unsigned short* Kb = Knb + (size_t)ti*64*F_;
            sk0 = *(const uint4*)(Kb + sm*64 + sc*16);
            sk1 = *(const uint4*)(Kb + sm*64 + sc*16 + 8);
            const unsigned short* Vb = Vnb + (size_t)sm*N_ + ti*64;
            sv0 = *(const uint4*)(Vb + sc*16);
            sv1 = *(const uint4*)(Vb + sc*16 + 8);
        } else {
            const unsigned short* Kb = Klb + (size_t)(ti-8)*64*F_;
            sk0 = *(const uint4*)(Kb + sm*64 + sc*16);
            sk1 = *(const uint4*)(Kb + sm*64 + sc*16 + 8);
            const unsigned short* Vb = Vlb + (size_t)sm*L_ + (ti-8)*64;
            sv0 = *(const uint4*)(Vb + sc*16);
            sv1 = *(const uint4*)(Vb + sc*16 + 8);
        }
    };
    auto write_tile = [&](int pb) {
        *(uint4*)&Ks[pb][sm*KSTR + sc*16]     = sk0;
        *(uint4*)&Ks[pb][sm*KSTR + sc*16 + 8] = sk1;
        *(uint4*)&Vt[pb][sm*KSTR + sc*16]     = sv0;
        *(uint4*)&Vt[pb][sm*KSTR + sc*16 + 8] = sv1;
    };

    load_tile(ti0);
    write_tile(0);
    __syncthreads();

    const int srcA = c + 16*((2*h) & 3);
    const int srcB = c + 16*((2*h + 1) & 3);
    const int hs   = h >> 1;

    for (int i = 0; i < TPS; ++i) {
        const int  ti  = ti0 + i;
        const bool isN = ti < 8;
        const int  pb  = i & 1;
        const bool nxt = (i + 1 < TPS);
        if (nxt) load_tile(ti + 1);

        f32x4 st[4] = {{0,0,0,0},{0,0,0,0},{0,0,0,0},{0,0,0,0}};
        #pragma unroll
        for (int ss = 0; ss < 4; ++ss) {
            const short8 kf0 = *(const short8*)&Ks[pb][(16*ss + c)*KSTR + 8*h];
            st[ss] = __builtin_amdgcn_mfma_f32_16x16x32_bf16(kf0, qf0, st[ss], 0,0,0);
            const short8 kf1 = *(const short8*)&Ks[pb][(16*ss + c)*KSTR + 32 + 8*h];
            st[ss] = __builtin_amdgcn_mfma_f32_16x16x32_bf16(kf1, qf1, st[ss], 0,0,0);
        }

        unsigned pk0[4], pk1[4];
        float psum = 0.f;
        #pragma unroll
        for (int ss = 0; ss < 4; ++ss) {
            #pragma unroll
            for (int r = 0; r < 4; ++r) { st[ss][r] = __expf(st[ss][r]); psum += st[ss][r]; }
            pk0[ss] = pack_bf(st[ss][0], st[ss][1]);
            pk1[ss] = pack_bf(st[ss][2], st[ss][3]);
        }
        if (isN) dsN += psum; else dsL += psum;

        #pragma unroll
        for (int k00 = 0; k00 < 2; ++k00) {
            const unsigned d0a = __shfl(pk0[2*k00+0], srcA);
            const unsigned d0b = __shfl(pk0[2*k00+1], srcA);
            const unsigned d1a = __shfl(pk1[2*k00+0], srcA);
            const unsigned d1b = __shfl(pk1[2*k00+1], srcA);
            const unsigned d2a = __shfl(pk0[2*k00+0], srcB);
            const unsigned d2b = __shfl(pk0[2*k00+1], srcB);
            const unsigned d3a = __shfl(pk1[2*k00+0], srcB);
            const unsigned d3b = __shfl(pk1[2*k00+1], srcB);
            const short8 bp = frag_from4(hs ? d0b : d0a, hs ? d1b : d1a,
                                         hs ? d2b : d2a, hs ? d3b : d3a);
            if (isN) {
                #pragma unroll
                for (int s2 = 0; s2 < 4; ++s2) {
                    const short8 af = *(const short8*)&Vt[pb][(16*s2 + c)*KSTR + 32*k00 + 8*h];
                    accN[s2] = __builtin_amdgcn_mfma_f32_16x16x32_bf16(af, bp, accN[s2], 0,0,0);
                }
            } else {
                #pragma unroll
                for (int s2 = 0; s2 < 4; ++s2) {
                    const short8 af = *(const short8*)&Vt[pb][(16*s2 + c)*KSTR + 32*k00 + 8*h];
                    accL[s2] = __builtin_amdgcn_mfma_f32_16x16x32_bf16(af, bp, accL[s2], 0,0,0);
                }
            }
        }

        if (nxt) {
            write_tile(pb ^ 1);
            __syncthreads();
        }
    }

    dsN += __shfl_xor(dsN, 16);  dsN += __shfl_xor(dsN, 32);
    dsL += __shfl_xor(dsL, 16);  dsL += __shfl_xor(dsL, 32);

    const int gt = b*T_ + t0 + w*16 + c;
    float* baseN = pacc + (((size_t)sl*(B_*T_) + gt)*2 + 0)*F_;
    float* baseL = baseN + F_;
    #pragma unroll
    for (int s2 = 0; s2 < 4; ++s2) {
        #pragma unroll
        for (int r = 0; r < 4; ++r) {
            baseN[s2*16 + 4*h + r] = accN[s2][r];
            baseL[s2*16 + 4*h + r] = accL[s2][r];
        }
    }
    if (h == 0) {
        pd[((size_t)sl*(B_*T_) + gt)*2 + 0] = dsN;
        pd[((size_t)sl*(B_*T_) + gt)*2 + 1] = dsL;
    }
}

// ---------------------------------------------------------------------------
// Combine slices + final feature softmax. One wave per target, lane = f.
// ---------------------------------------------------------------------------
__global__ __launch_bounds__(256)
void combine_kernel(const float* __restrict__ pacc, const float* __restrict__ pd,
                    float* __restrict__ out)
{
    const int gt = (blockIdx.x * 256 + threadIdx.x) >> 6;
    const int f  = threadIdx.x & 63;

    float aN = 0.f, aL = 0.f, dN = 0.f, dL = 0.f;
    #pragma unroll
    for (int s = 0; s < SLICES; ++s) {
        const size_t base = ((size_t)s*(B_*T_) + gt)*2;
        aN += pacc[(base + 0)*F_ + f];
        aL += pacc[(base + 1)*F_ + f];
        dN += pd[base + 0];
        dL += pd[base + 1];
    }
    float lg = aN / dN + aL / dL;
    float mx = lg;
    #pragma unroll
    for (int off = 1; off < 64; off <<= 1) mx = fmaxf(mx, __shfl_xor(mx, off));
    const float e = __expf(lg - mx);
    float ssum = e;
    #pragma unroll
    for (int off = 1; off < 64; off <<= 1) ssum += __shfl_xor(ssum, off);
    out[(size_t)gt*F_ + f] = e / ssum;
}

// ---------------------------------------------------------------------------
extern "C" void kernel_launch(void* const* d_in, const int* in_sizes, int n_in,
                              void* d_out, int out_size, void* d_ws, size_t ws_size,
                              hipStream_t stream)
{
    const float* root   = (const float*)d_in[0];
    const float* node   = (const float*)d_in[1];
    const float* leaf   = (const float*)d_in[2];
    const float* target = (const float*)d_in[3];
    const float* Wq   = (const float*)d_in[4];
    const float* bq   = (const float*)d_in[5];
    const float* Wk   = (const float*)d_in[6];
    const float* bk   = (const float*)d_in[7];
    const float* Wv   = (const float*)d_in[8];
    const float* bv   = (const float*)d_in[9];
    const float* Wagg = (const float*)d_in[10];
    const float* bagg = (const float*)d_in[11];
    float* out = (float*)d_out;

    // workspace layout (bytes), ~29.7 MB
    char* wp = (char*)d_ws;
    unsigned short* q_bf  = (unsigned short*)wp; wp += (size_t)B_*T_*F_*2;   // 1 MB
    unsigned short* nk_bf = (unsigned short*)wp; wp += (size_t)B_*N_*F_*2;   // 0.5 MB
    unsigned short* lk_bf = (unsigned short*)wp; wp += (size_t)B_*L_*F_*2;   // 4 MB
    unsigned short* lvt   = (unsigned short*)wp; wp += (size_t)B_*F_*L_*2;   // 4 MB
    unsigned short* nht   = (unsigned short*)wp; wp += (size_t)B_*F_*N_*2;   // 0.5 MB
    unsigned short* Wq_t  = (unsigned short*)wp; wp += (size_t)64*D_*2;      // 64 KB
    unsigned short* Wkv_t = (unsigned short*)wp; wp += (size_t)128*D_*2;     // 128 KB
    float* node_v = (float*)wp; wp += (size_t)B_*N_*F_*4;                    // 1 MB
    float* agg    = (float*)wp; wp += (size_t)B_*L_*4;                       // 128 KB
    float* Tnext  = (float*)wp; wp += (size_t)B_*N_*F_*4;                    // 1 MB
    float* bq_s   = (float*)wp; wp += 512;
    float* bkv    = (float*)wp; wp += 512;
    float* pacc   = (float*)wp; wp += (size_t)SLICES*B_*T_*2*F_*4;           // 16 MB
    float* pd     = (float*)wp;                                              // 256 KB

    prep_kernel<<<193, 64, 0, stream>>>(Wq, bq, Wk, bk, Wv, bv, Wq_t, Wkv_t, bq_s, bkv);
    proj_gemm<0><<<(B_*T_)/64, 256, 0, stream>>>(target, Wq_t, bq_s,
        nullptr, nullptr, q_bf, nullptr, nullptr, nullptr);
    proj_gemm<1><<<(B_*N_)/64, 256, 0, stream>>>(node, Wkv_t, bkv,
        nullptr, nullptr, nk_bf, node_v, nullptr, nullptr);
    proj_gemm<2><<<(B_*L_)/64, 256, 0, stream>>>(leaf, Wkv_t, bkv,
        Wagg, bagg, lk_bf, nullptr, lvt, agg);
    scan_kernel<<<128, 256, 0, stream>>>(lvt, node_v, root, Tnext);
    node_hat_kernel<<<B_*N_, 64, 0, stream>>>(Tnext, agg, lvt, node_v, root, nht);
    attn_kernel<<<B_*(T_/64)*SLICES, 256, 0, stream>>>(q_bf, nk_bf, nht, lk_bf, lvt, pacc, pd);
    combine_kernel<<<(B_*T_)/4, 256, 0, stream>>>(pacc, pd, out);
}

// Round 7
// 96.664 us; speedup vs baseline: 7.3233x; 1.0312x over previous
//
#include <hip/hip_runtime.h>

// DecoderAttention: B=8, T=1024, N=512, L=4096, D=512, F=64, BR=8
#define B_ 8
#define T_ 1024
#define N_ 512
#define L_ 4096
#define D_ 512
#define F_ 64
#define SLICES 4
#define TPS 18    // tiles per slice (72 total: 8 node + 64 leaf)
#define KSTR 72   // attn LDS row stride (bf16) for K / V^T tiles
#define XSTR 520  // proj LDS row stride (bf16)

typedef __attribute__((ext_vector_type(8))) short short8;
typedef __attribute__((ext_vector_type(4))) float f32x4;

__device__ __forceinline__ unsigned short f2bf(float x){
    unsigned u = __builtin_bit_cast(unsigned, x);
    u += 0x7FFFu + ((u >> 16) & 1u);           // RNE
    return (unsigned short)(u >> 16);
}
__device__ __forceinline__ unsigned pack_bf(float lo, float hi){
    return (unsigned)f2bf(lo) | ((unsigned)f2bf(hi) << 16);
}
__device__ __forceinline__ float bf2f(short s){
    return __builtin_bit_cast(float, ((unsigned)(unsigned short)s) << 16);
}
__device__ __forceinline__ short8 frag_from4(unsigned d0, unsigned d1, unsigned d2, unsigned d3){
    union { unsigned u[4]; short8 s; } t;
    t.u[0] = d0; t.u[1] = d1; t.u[2] = d2; t.u[3] = d3;
    return t.s;
}

// ---------------------------------------------------------------------------
// Weight prep: transposed bf16 weights + bias vectors.
// ---------------------------------------------------------------------------
__global__ __launch_bounds__(64)
void prep_kernel(const float* __restrict__ Wq, const float* __restrict__ bq,
                 const float* __restrict__ Wk, const float* __restrict__ bk,
                 const float* __restrict__ Wv, const float* __restrict__ bv,
                 unsigned short* __restrict__ Wq_t, unsigned short* __restrict__ Wkv_t,
                 float* __restrict__ bq_s, float* __restrict__ bkv)
{
    const int n = blockIdx.x;
    const int lane = threadIdx.x;
    if (n == 192) {
        bq_s[lane]   = bq[lane] * 0.125f;
        bkv[lane]    = bk[lane];
        bkv[64+lane] = bv[lane];
        return;
    }
    const int d0 = lane * 8;
    unsigned short t[8];
    if (n < 64) {
        #pragma unroll
        for (int j = 0; j < 8; ++j) t[j] = f2bf(Wq[(size_t)(d0+j)*F_ + n] * 0.125f);
        *(uint4*)&Wq_t[(size_t)n*D_ + d0] = make_uint4(
            (unsigned)t[0]|((unsigned)t[1]<<16), (unsigned)t[2]|((unsigned)t[3]<<16),
            (unsigned)t[4]|((unsigned)t[5]<<16), (unsigned)t[6]|((unsigned)t[7]<<16));
    } else {
        const int nn  = n - 64;
        const float* W = (nn < 64) ? Wk : Wv;
        const int col = nn & 63;
        #pragma unroll
        for (int j = 0; j < 8; ++j) t[j] = f2bf(W[(size_t)(d0+j)*F_ + col]);
        *(uint4*)&Wkv_t[(size_t)nn*D_ + d0] = make_uint4(
            (unsigned)t[0]|((unsigned)t[1]<<16), (unsigned)t[2]|((unsigned)t[3]<<16),
            (unsigned)t[4]|((unsigned)t[5]<<16), (unsigned)t[6]|((unsigned)t[7]<<16));
    }
}

// ---------------------------------------------------------------------------
// MFMA projection GEMM, weights-in-registers (verified round 6, unchanged).
// ---------------------------------------------------------------------------
template<int MODE>
__global__ __launch_bounds__(256, 2)
void proj_gemm(const float* __restrict__ X,
               const unsigned short* __restrict__ Wt,
               const float* __restrict__ bias,
               const float* __restrict__ Wagg,
               const float* __restrict__ bagg,
               unsigned short* __restrict__ outK,
               float* __restrict__ outVf,
               unsigned short* __restrict__ outVt,
               float* __restrict__ outAgg)
{
    constexpr int NPW = (MODE == 0) ? 1 : 2;
    __shared__ unsigned short Xs[64 * XSTR];                     // 65 KB
    __shared__ unsigned short Vt_lds[(MODE == 2) ? (64*72) : 4]; // 9 KB leaf

    const int tid = threadIdx.x;
    const int r0  = blockIdx.x * 64;
    const int w = tid >> 6, l = tid & 63, c = l & 15, h = l >> 4;

    // ---- B-frag preload (issued first; latency hides under staging) ----
    short8 breg[NPW][16];
    #pragma unroll
    for (int p = 0; p < NPW; ++p) {
        const unsigned short* wrow = Wt + (size_t)(16*(NPW*w + p) + c)*D_ + 8*h;
        #pragma unroll
        for (int kk = 0; kk < 16; ++kk)
            breg[p][kk] = *(const short8*)(wrow + kk*32);
    }

    // ---- stage 64x512 f32 -> bf16 LDS ----
    const float4* xsrc = (const float4*)(X + (size_t)r0 * D_);
    #pragma unroll 4
    for (int j = 0; j < 32; ++j) {
        const int s = tid + j * 256;             // float4 slot; 128 per row
        const float4 v = xsrc[s];
        *(uint2*)&Xs[(s >> 7)*XSTR + (s & 127)*4] =
            make_uint2(pack_bf(v.x, v.y), pack_bf(v.z, v.w));
    }
    __syncthreads();

    // ---- kk loop: pure ds_read + MFMA ----
    f32x4 acc[NPW][4];
    #pragma unroll
    for (int p = 0; p < NPW; ++p)
        #pragma unroll
        for (int m = 0; m < 4; ++m) acc[p][m] = (f32x4){0,0,0,0};

    #pragma unroll
    for (int kk = 0; kk < 16; ++kk) {
        #pragma unroll
        for (int m = 0; m < 4; ++m) {
            const short8 af = *(const short8*)&Xs[(16*m + c)*XSTR + kk*32 + 8*h];
            #pragma unroll
            for (int p = 0; p < NPW; ++p)
                acc[p][m] = __builtin_amdgcn_mfma_f32_16x16x32_bf16(af, breg[p][kk], acc[p][m], 0,0,0);
        }
    }

    // ---- epilogues ----
    #pragma unroll
    for (int p = 0; p < NPW; ++p) {
        const int s2g = NPW*w + p;
        const float bc = bias[16*s2g + c];
        if (MODE == 0 || s2g < 4) {
            #pragma unroll
            for (int m = 0; m < 4; ++m)
                #pragma unroll
                for (int r = 0; r < 4; ++r)
                    outK[(size_t)(r0 + 16*m + 4*h + r)*F_ + 16*s2g + c] = f2bf(acc[p][m][r] + bc);
        } else if (MODE == 1) {
            #pragma unroll
            for (int m = 0; m < 4; ++m)
                #pragma unroll
                for (int r = 0; r < 4; ++r)
                    outVf[(size_t)(r0 + 16*m + 4*h + r)*F_ + 16*(s2g-4) + c] = acc[p][m][r] + bc;
        } else {
            #pragma unroll
            for (int m = 0; m < 4; ++m)
                #pragma unroll
                for (int r = 0; r < 4; ++r)
                    Vt_lds[(16*(s2g-4) + c)*72 + 16*m + 4*h + r] = f2bf(acc[p][m][r] + bc);
        }
    }

    if constexpr (MODE == 2) {
        // agg logit per leaf row from bf16 Xs
        {
            const int row = tid >> 2, qd = tid & 3;
            const unsigned short* xr = &Xs[row*XSTR + qd*128];
            const float* wr = Wagg + qd*128;
            float p = 0.f;
            #pragma unroll
            for (int j = 0; j < 16; ++j) {
                const short8 xv = *(const short8*)(xr + j*8);
                const float4 wa0 = *(const float4*)(wr + j*8);
                const float4 wa1 = *(const float4*)(wr + j*8 + 4);
                p += bf2f(xv[0])*wa0.x + bf2f(xv[1])*wa0.y
                   + bf2f(xv[2])*wa0.z + bf2f(xv[3])*wa0.w
                   + bf2f(xv[4])*wa1.x + bf2f(xv[5])*wa1.y
                   + bf2f(xv[6])*wa1.z + bf2f(xv[7])*wa1.w;
            }
            p += __shfl_xor(p, 1);
            p += __shfl_xor(p, 2);
            if (qd == 0) outAgg[r0 + row] = p + bagg[0];
        }
        __syncthreads();
        // coalesced V^T writeout
        {
            const int f = tid >> 2, seg = tid & 3;
            const int b = r0 >> 12, l0 = r0 & (L_ - 1);
            const uint4 a0 = *(const uint4*)&Vt_lds[f*72 + seg*16];
            const uint4 a1 = *(const uint4*)&Vt_lds[f*72 + seg*16 + 8];
            unsigned short* dst = outVt + ((size_t)(b*F_ + f))*L_ + l0 + seg*16;
            *(uint4*)dst = a0;
            *(uint4*)(dst + 8) = a1;
        }
    }
}

// ---------------------------------------------------------------------------
// Suffix scan over node groups; builds group interp sums G from lvt.
// ---------------------------------------------------------------------------
__global__ __launch_bounds__(256)
void scan_kernel(const unsigned short* __restrict__ lvt,
                 const float* __restrict__ node_v,
                 const float* __restrict__ root,
                 float* __restrict__ Tnext)
{
    const int gtid = blockIdx.x * 256 + threadIdx.x;
    const int wv   = gtid >> 6;
    const int lane = threadIdx.x & 63;
    const int b = wv >> 6;
    const int f = wv & 63;

    const unsigned short* vt = lvt + ((size_t)(b*F_ + f))*L_ + lane*64;
    const float rootf = root[b*F_ + f];
    float gv[8];
    #pragma unroll
    for (int g = 0; g < 8; ++g) {
        const short8 xv = *(const short8*)(vt + g*8);
        const float s8 = bf2f(xv[0])+bf2f(xv[1])+bf2f(xv[2])+bf2f(xv[3])
                       + bf2f(xv[4])+bf2f(xv[5])+bf2f(xv[6])+bf2f(xv[7]);
        const float nv = node_v[((size_t)(b*N_ + lane*8 + g))*F_ + f];
        gv[g] = (s8 + 8.f*(rootf + nv)) * (1.f/3.f);
    }

    float s[9];
    s[8] = 0.f;
    #pragma unroll
    for (int j = 7; j >= 0; --j) s[j] = s[j+1] + gv[j];

    float x = s[0];
    const float lsum = x;
    #pragma unroll
    for (int off = 1; off < 64; off <<= 1) {
        float t = __shfl_down(x, off);
        if (lane + off < 64) x += t;
    }
    const float excl = x - lsum;

    float* outp = Tnext + ((size_t)(b*N_ + lane*8))*F_ + f;
    #pragma unroll
    for (int j = 0; j < 8; ++j) outp[(size_t)j*F_] = excl + s[j+1];
}

// ---------------------------------------------------------------------------
// node_hat -> transposed bf16 [B][F][N].
// ---------------------------------------------------------------------------
__global__ __launch_bounds__(64)
void node_hat_kernel(const float* __restrict__ Tnext, const float* __restrict__ agg,
                     const unsigned short* __restrict__ lvt, const float* __restrict__ node_v,
                     const float* __restrict__ root, unsigned short* __restrict__ nh_t)
{
    const int bn = blockIdx.x;
    const int b = bn >> 9;
    const int n = bn & (N_ - 1);
    const int f = threadIdx.x;

    float a[8];
    #pragma unroll
    for (int c = 0; c < 8; ++c) a[c] = agg[(size_t)b*L_ + n*8 + c];
    float mx = a[0];
    #pragma unroll
    for (int c = 1; c < 8; ++c) mx = fmaxf(mx, a[c]);
    float wgt[8]; float wsum = 0.f;
    #pragma unroll
    for (int c = 0; c < 8; ++c) { wgt[c] = __expf(a[c] - mx); wsum += wgt[c]; }

    const float tn    = Tnext[(size_t)bn*F_ + f];
    const float rootf = root[b*F_ + f];
    const float nv    = node_v[(size_t)bn*F_ + f];
    const short8 lv8  = *(const short8*)(lvt + ((size_t)(b*F_ + f))*L_ + n*8);
    float run = 0.f, acc = 0.f;
    #pragma unroll
    for (int c = 7; c >= 0; --c) {
        const int l = n*8 + c;
        const float interp = (rootf + nv + bf2f(lv8[c])) * (1.f/3.f);
        run += interp;
        const float up = (tn + run) / (float)(L_ - l);
        acc = fmaf(wgt[c], up, acc);
    }
    nh_t[((size_t)(b*F_ + f))*N_ + n] = f2bf(acc / wsum);
}

// ---------------------------------------------------------------------------
// MFMA dual-softmax attention, transpose-free. ROUND 7: 8 waves/block
// (t-tile 128), 256 blocks -> 16 waves/CU (4/SIMD) for latency hiding.
// Per-wave work and fragment math identical to the verified round-4 kernel.
// ---------------------------------------------------------------------------
__global__ __launch_bounds__(512, 4)
void attn_kernel(const unsigned short* __restrict__ qb,
                 const unsigned short* __restrict__ nk,
                 const unsigned short* __restrict__ nht,
                 const unsigned short* __restrict__ lk,
                 const unsigned short* __restrict__ lvt,
                 float* __restrict__ pacc, float* __restrict__ pd)
{
    __shared__ unsigned short Ks[2][64*KSTR];   // 18 KB
    __shared__ unsigned short Vt[2][64*KSTR];   // 18 KB

    // 256 blocks; blockIdx&7 = XCD -> 32 consecutive wg per XCD = one batch
    // (bf16 K/V ~1.2 MB -> L2-fits per XCD).
    const int wg  = (blockIdx.x & 7) * 32 + (blockIdx.x >> 3);
    const int b   = wg >> 5;
    const int sl  = (wg >> 3) & 3;
    const int t0  = (wg & 7) * 128;

    const int tid = threadIdx.x;
    const int w   = tid >> 6;      // wave 0..7, owns t rows t0+16w .. t0+16w+15
    const int l   = tid & 63;
    const int c   = l & 15;
    const int h   = l >> 4;
    const int sm  = tid >> 3;      // staging row 0..63
    const int sc  = tid & 7;       // staging 8-col (16B) chunk

    const unsigned short* qrow = qb + ((size_t)(b*T_ + t0 + w*16 + c))*F_ + 8*h;
    const short8 qf0 = *(const short8*)qrow;
    const short8 qf1 = *(const short8*)(qrow + 32);

    f32x4 accN[4] = {{0,0,0,0},{0,0,0,0},{0,0,0,0},{0,0,0,0}};
    f32x4 accL[4] = {{0,0,0,0},{0,0,0,0},{0,0,0,0},{0,0,0,0}};
    float dsN = 0.f, dsL = 0.f;

    const unsigned short* Knb = nk  + (size_t)b*N_*F_;
    const unsigned short* Klb = lk  + (size_t)b*L_*F_;
    const unsigned short* Vnb = nht + (size_t)b*F_*N_;   // [F][N]
    const unsigned short* Vlb = lvt + (size_t)b*F_*L_;   // [F][L]

    const int ti0 = sl * TPS;

    uint4 sk0, sv0;
    auto load_tile = [&](int ti) {
        if (ti < 8) {
            sk0 = *(const uint4*)(Knb + (size_t)ti*64*F_ + sm*64 + sc*8);
            sv0 = *(const uint4*)(Vnb + (size_t)sm*N_ + ti*64 + sc*8);
        } else {
            sk0 = *(const uint4*)(Klb + (size_t)(ti-8)*64*F_ + sm*64 + sc*8);
            sv0 = *(const uint4*)(Vlb + (size_t)sm*L_ + (ti-8)*64 + sc*8);
        }
    };
    auto write_tile = [&](int pb) {
        *(uint4*)&Ks[pb][sm*KSTR + sc*8] = sk0;
        *(uint4*)&Vt[pb][sm*KSTR + sc*8] = sv0;
    };

    load_tile(ti0);
    write_tile(0);
    __syncthreads();

    const int srcA = c + 16*((2*h) & 3);
    const int srcB = c + 16*((2*h + 1) & 3);
    const int hs   = h >> 1;

    for (int i = 0; i < TPS; ++i) {
        const int  ti  = ti0 + i;
        const bool isN = ti < 8;
        const int  pb  = i & 1;
        const bool nxt = (i + 1 < TPS);
        if (nxt) load_tile(ti + 1);

        f32x4 st[4] = {{0,0,0,0},{0,0,0,0},{0,0,0,0},{0,0,0,0}};
        #pragma unroll
        for (int ss = 0; ss < 4; ++ss) {
            const short8 kf0 = *(const short8*)&Ks[pb][(16*ss + c)*KSTR + 8*h];
            st[ss] = __builtin_amdgcn_mfma_f32_16x16x32_bf16(kf0, qf0, st[ss], 0,0,0);
            const short8 kf1 = *(const short8*)&Ks[pb][(16*ss + c)*KSTR + 32 + 8*h];
            st[ss] = __builtin_amdgcn_mfma_f32_16x16x32_bf16(kf1, qf1, st[ss], 0,0,0);
        }

        unsigned pk0[4], pk1[4];
        float psum = 0.f;
        #pragma unroll
        for (int ss = 0; ss < 4; ++ss) {
            #pragma unroll
            for (int r = 0; r < 4; ++r) { st[ss][r] = __expf(st[ss][r]); psum += st[ss][r]; }
            pk0[ss] = pack_bf(st[ss][0], st[ss][1]);
            pk1[ss] = pack_bf(st[ss][2], st[ss][3]);
        }
        if (isN) dsN += psum; else dsL += psum;

        #pragma unroll
        for (int k00 = 0; k00 < 2; ++k00) {
            const unsigned d0a = __shfl(pk0[2*k00+0], srcA);
            const unsigned d0b = __shfl(pk0[2*k00+1], srcA);
            const unsigned d1a = __shfl(pk1[2*k00+0], srcA);
            const unsigned d1b = __shfl(pk1[2*k00+1], srcA);
            const unsigned d2a = __shfl(pk0[2*k00+0], srcB);
            const unsigned d2b = __shfl(pk0[2*k00+1], srcB);
            const unsigned d3a = __shfl(pk1[2*k00+0], srcB);
            const unsigned d3b = __shfl(pk1[2*k00+1], srcB);
            const short8 bp = frag_from4(hs ? d0b : d0a, hs ? d1b : d1a,
                                         hs ? d2b : d2a, hs ? d3b : d3a);
            if (isN) {
                #pragma unroll
                for (int s2 = 0; s2 < 4; ++s2) {
                    const short8 af = *(const short8*)&Vt[pb][(16*s2 + c)*KSTR + 32*k00 + 8*h];
                    accN[s2] = __builtin_amdgcn_mfma_f32_16x16x32_bf16(af, bp, accN[s2], 0,0,0);
                }
            } else {
                #pragma unroll
                for (int s2 = 0; s2 < 4; ++s2) {
                    const short8 af = *(const short8*)&Vt[pb][(16*s2 + c)*KSTR + 32*k00 + 8*h];
                    accL[s2] = __builtin_amdgcn_mfma_f32_16x16x32_bf16(af, bp, accL[s2], 0,0,0);
                }
            }
        }

        if (nxt) {
            write_tile(pb ^ 1);
            __syncthreads();
        }
    }

    dsN += __shfl_xor(dsN, 16);  dsN += __shfl_xor(dsN, 32);
    dsL += __shfl_xor(dsL, 16);  dsL += __shfl_xor(dsL, 32);

    const int gt = b*T_ + t0 + w*16 + c;
    float* baseN = pacc + (((size_t)sl*(B_*T_) + gt)*2 + 0)*F_;
    float* baseL = baseN + F_;
    #pragma unroll
    for (int s2 = 0; s2 < 4; ++s2) {
        #pragma unroll
        for (int r = 0; r < 4; ++r) {
            baseN[s2*16 + 4*h + r] = accN[s2][r];
            baseL[s2*16 + 4*h + r] = accL[s2][r];
        }
    }
    if (h == 0) {
        pd[((size_t)sl*(B_*T_) + gt)*2 + 0] = dsN;
        pd[((size_t)sl*(B_*T_) + gt)*2 + 1] = dsL;
    }
}

// ---------------------------------------------------------------------------
// Combine slices + final feature softmax. One wave per target, lane = f.
// ---------------------------------------------------------------------------
__global__ __launch_bounds__(256)
void combine_kernel(const float* __restrict__ pacc, const float* __restrict__ pd,
                    float* __restrict__ out)
{
    const int gt = (blockIdx.x * 256 + threadIdx.x) >> 6;
    const int f  = threadIdx.x & 63;

    float aN = 0.f, aL = 0.f, dN = 0.f, dL = 0.f;
    #pragma unroll
    for (int s = 0; s < SLICES; ++s) {
        const size_t base = ((size_t)s*(B_*T_) + gt)*2;
        aN += pacc[(base + 0)*F_ + f];
        aL += pacc[(base + 1)*F_ + f];
        dN += pd[base + 0];
        dL += pd[base + 1];
    }
    float lg = aN / dN + aL / dL;
    float mx = lg;
    #pragma unroll
    for (int off = 1; off < 64; off <<= 1) mx = fmaxf(mx, __shfl_xor(mx, off));
    const float e = __expf(lg - mx);
    float ssum = e;
    #pragma unroll
    for (int off = 1; off < 64; off <<= 1) ssum += __shfl_xor(ssum, off);
    out[(size_t)gt*F_ + f] = e / ssum;
}

// ---------------------------------------------------------------------------
extern "C" void kernel_launch(void* const* d_in, const int* in_sizes, int n_in,
                              void* d_out, int out_size, void* d_ws, size_t ws_size,
                              hipStream_t stream)
{
    const float* root   = (const float*)d_in[0];
    const float* node   = (const float*)d_in[1];
    const float* leaf   = (const float*)d_in[2];
    const float* target = (const float*)d_in[3];
    const float* Wq   = (const float*)d_in[4];
    const float* bq   = (const float*)d_in[5];
    const float* Wk   = (const float*)d_in[6];
    const float* bk   = (const float*)d_in[7];
    const float* Wv   = (const float*)d_in[8];
    const float* bv   = (const float*)d_in[9];
    const float* Wagg = (const float*)d_in[10];
    const float* bagg = (const float*)d_in[11];
    float* out = (float*)d_out;

    // workspace layout (bytes), ~29.7 MB
    char* wp = (char*)d_ws;
    unsigned short* q_bf  = (unsigned short*)wp; wp += (size_t)B_*T_*F_*2;   // 1 MB
    unsigned short* nk_bf = (unsigned short*)wp; wp += (size_t)B_*N_*F_*2;   // 0.5 MB
    unsigned short* lk_bf = (unsigned short*)wp; wp += (size_t)B_*L_*F_*2;   // 4 MB
    unsigned short* lvt   = (unsigned short*)wp; wp += (size_t)B_*F_*L_*2;   // 4 MB
    unsigned short* nht   = (unsigned short*)wp; wp += (size_t)B_*F_*N_*2;   // 0.5 MB
    unsigned short* Wq_t  = (unsigned short*)wp; wp += (size_t)64*D_*2;      // 64 KB
    unsigned short* Wkv_t = (unsigned short*)wp; wp += (size_t)128*D_*2;     // 128 KB
    float* node_v = (float*)wp; wp += (size_t)B_*N_*F_*4;                    // 1 MB
    float* agg    = (float*)wp; wp += (size_t)B_*L_*4;                       // 128 KB
    float* Tnext  = (float*)wp; wp += (size_t)B_*N_*F_*4;                    // 1 MB
    float* bq_s   = (float*)wp; wp += 512;
    float* bkv    = (float*)wp; wp += 512;
    float* pacc   = (float*)wp; wp += (size_t)SLICES*B_*T_*2*F_*4;           // 16 MB
    float* pd     = (float*)wp;                                              // 256 KB

    prep_kernel<<<193, 64, 0, stream>>>(Wq, bq, Wk, bk, Wv, bv, Wq_t, Wkv_t, bq_s, bkv);
    proj_gemm<0><<<(B_*T_)/64, 256, 0, stream>>>(target, Wq_t, bq_s,
        nullptr, nullptr, q_bf, nullptr, nullptr, nullptr);
    proj_gemm<1><<<(B_*N_)/64, 256, 0, stream>>>(node, Wkv_t, bkv,
        nullptr, nullptr, nk_bf, node_v, nullptr, nullptr);
    proj_gemm<2><<<(B_*L_)/64, 256, 0, stream>>>(leaf, Wkv_t, bkv,
        Wagg, bagg, lk_bf, nullptr, lvt, agg);
    scan_kernel<<<128, 256, 0, stream>>>(lvt, node_v, root, Tnext);
    node_hat_kernel<<<B_*N_, 64, 0, stream>>>(Tnext, agg, lvt, node_v, root, nht);
    attn_kernel<<<B_*(T_/128)*SLICES, 512, 0, stream>>>(q_bf, nk_bf, nht, lk_bf, lvt, pacc, pd);
    combine_kernel<<<(B_*T_)/4, 256, 0, stream>>>(pacc, pd, out);
}

// Round 8
// 80.928 us; speedup vs baseline: 8.7473x; 1.1944x over previous
//
#include <hip/hip_runtime.h>

// DecoderAttention: B=8, T=1024, N=512, L=4096, D=512, F=64, BR=8
#define B_ 8
#define T_ 1024
#define N_ 512
#define L_ 4096
#define D_ 512
#define F_ 64
#define SLICES 8
#define TPS 9     // tiles per slice (72 total: 8 node + 64 leaf)
#define KSTR 72   // attn LDS row stride (bf16) for K / V^T tiles
#define XSTR 520  // proj LDS row stride (bf16)

typedef __attribute__((ext_vector_type(8))) short short8;
typedef __attribute__((ext_vector_type(4))) float f32x4;

__device__ __forceinline__ unsigned short f2bf(float x){
    unsigned u = __builtin_bit_cast(unsigned, x);
    u += 0x7FFFu + ((u >> 16) & 1u);           // RNE
    return (unsigned short)(u >> 16);
}
__device__ __forceinline__ unsigned pack_bf(float lo, float hi){
    return (unsigned)f2bf(lo) | ((unsigned)f2bf(hi) << 16);
}
__device__ __forceinline__ float bf2f(unsigned short s){
    return __builtin_bit_cast(float, ((unsigned)s) << 16);
}
__device__ __forceinline__ short8 frag_from4(unsigned d0, unsigned d1, unsigned d2, unsigned d3){
    union { unsigned u[4]; short8 s; } t;
    t.u[0] = d0; t.u[1] = d1; t.u[2] = d2; t.u[3] = d3;
    return t.s;
}

// ---------------------------------------------------------------------------
// Weight prep: transposed bf16 weights + bias vectors.
// ---------------------------------------------------------------------------
__global__ __launch_bounds__(64)
void prep_kernel(const float* __restrict__ Wq, const float* __restrict__ bq,
                 const float* __restrict__ Wk, const float* __restrict__ bk,
                 const float* __restrict__ Wv, const float* __restrict__ bv,
                 unsigned short* __restrict__ Wq_t, unsigned short* __restrict__ Wkv_t,
                 float* __restrict__ bq_s, float* __restrict__ bkv)
{
    const int n = blockIdx.x;
    const int lane = threadIdx.x;
    if (n == 192) {
        bq_s[lane]   = bq[lane] * 0.125f;
        bkv[lane]    = bk[lane];
        bkv[64+lane] = bv[lane];
        return;
    }
    const int d0 = lane * 8;
    unsigned short t[8];
    if (n < 64) {
        #pragma unroll
        for (int j = 0; j < 8; ++j) t[j] = f2bf(Wq[(size_t)(d0+j)*F_ + n] * 0.125f);
        *(uint4*)&Wq_t[(size_t)n*D_ + d0] = make_uint4(
            (unsigned)t[0]|((unsigned)t[1]<<16), (unsigned)t[2]|((unsigned)t[3]<<16),
            (unsigned)t[4]|((unsigned)t[5]<<16), (unsigned)t[6]|((unsigned)t[7]<<16));
    } else {
        const int nn  = n - 64;
        const float* W = (nn < 64) ? Wk : Wv;
        const int col = nn & 63;
        #pragma unroll
        for (int j = 0; j < 8; ++j) t[j] = f2bf(W[(size_t)(d0+j)*F_ + col]);
        *(uint4*)&Wkv_t[(size_t)nn*D_ + d0] = make_uint4(
            (unsigned)t[0]|((unsigned)t[1]<<16), (unsigned)t[2]|((unsigned)t[3]<<16),
            (unsigned)t[4]|((unsigned)t[5]<<16), (unsigned)t[6]|((unsigned)t[7]<<16));
    }
}

// ---------------------------------------------------------------------------
// Projection GEMM body (verified round 6), as a device function so one fused
// kernel dispatches leaf/target/node blocks. Weights-in-registers.
// ---------------------------------------------------------------------------
template<int MODE>
__device__ __forceinline__ void proj_body(
    int r0, unsigned short* Xs, unsigned short* Vt_lds,
    const float* __restrict__ X,
    const unsigned short* __restrict__ Wt,
    const float* __restrict__ bias,
    const float* __restrict__ Wagg, const float* __restrict__ bagg,
    unsigned short* __restrict__ outK, float* __restrict__ outVf,
    unsigned short* __restrict__ outVt, float* __restrict__ outAgg)
{
    constexpr int NPW = (MODE == 0) ? 1 : 2;
    const int tid = threadIdx.x;
    const int w = tid >> 6, l = tid & 63, c = l & 15, h = l >> 4;

    // B-frag preload (latency hides under staging)
    short8 breg[NPW][16];
    #pragma unroll
    for (int p = 0; p < NPW; ++p) {
        const unsigned short* wrow = Wt + (size_t)(16*(NPW*w + p) + c)*D_ + 8*h;
        #pragma unroll
        for (int kk = 0; kk < 16; ++kk)
            breg[p][kk] = *(const short8*)(wrow + kk*32);
    }

    // stage 64x512 f32 -> bf16 LDS
    const float4* xsrc = (const float4*)(X + (size_t)r0 * D_);
    #pragma unroll 4
    for (int j = 0; j < 32; ++j) {
        const int s = tid + j * 256;
        const float4 v = xsrc[s];
        *(uint2*)&Xs[(s >> 7)*XSTR + (s & 127)*4] =
            make_uint2(pack_bf(v.x, v.y), pack_bf(v.z, v.w));
    }
    __syncthreads();

    f32x4 acc[NPW][4];
    #pragma unroll
    for (int p = 0; p < NPW; ++p)
        #pragma unroll
        for (int m = 0; m < 4; ++m) acc[p][m] = (f32x4){0,0,0,0};

    #pragma unroll
    for (int kk = 0; kk < 16; ++kk) {
        #pragma unroll
        for (int m = 0; m < 4; ++m) {
            const short8 af = *(const short8*)&Xs[(16*m + c)*XSTR + kk*32 + 8*h];
            #pragma unroll
            for (int p = 0; p < NPW; ++p)
                acc[p][m] = __builtin_amdgcn_mfma_f32_16x16x32_bf16(af, breg[p][kk], acc[p][m], 0,0,0);
        }
    }

    #pragma unroll
    for (int p = 0; p < NPW; ++p) {
        const int s2g = NPW*w + p;
        const float bc = bias[16*s2g + c];
        if (MODE == 0 || s2g < 4) {
            #pragma unroll
            for (int m = 0; m < 4; ++m)
                #pragma unroll
                for (int r = 0; r < 4; ++r)
                    outK[(size_t)(r0 + 16*m + 4*h + r)*F_ + 16*s2g + c] = f2bf(acc[p][m][r] + bc);
        } else if (MODE == 1) {
            #pragma unroll
            for (int m = 0; m < 4; ++m)
                #pragma unroll
                for (int r = 0; r < 4; ++r)
                    outVf[(size_t)(r0 + 16*m + 4*h + r)*F_ + 16*(s2g-4) + c] = acc[p][m][r] + bc;
        } else {
            #pragma unroll
            for (int m = 0; m < 4; ++m)
                #pragma unroll
                for (int r = 0; r < 4; ++r)
                    Vt_lds[(16*(s2g-4) + c)*72 + 16*m + 4*h + r] = f2bf(acc[p][m][r] + bc);
        }
    }

    if constexpr (MODE == 2) {
        // agg logit per leaf row from bf16 Xs
        {
            const int row = tid >> 2, qd = tid & 3;
            const unsigned short* xr = &Xs[row*XSTR + qd*128];
            const float* wr = Wagg + qd*128;
            float p = 0.f;
            #pragma unroll
            for (int j = 0; j < 16; ++j) {
                const short8 xv = *(const short8*)(xr + j*8);
                const float4 wa0 = *(const float4*)(wr + j*8);
                const float4 wa1 = *(const float4*)(wr + j*8 + 4);
                p += bf2f((unsigned short)xv[0])*wa0.x + bf2f((unsigned short)xv[1])*wa0.y
                   + bf2f((unsigned short)xv[2])*wa0.z + bf2f((unsigned short)xv[3])*wa0.w
                   + bf2f((unsigned short)xv[4])*wa1.x + bf2f((unsigned short)xv[5])*wa1.y
                   + bf2f((unsigned short)xv[6])*wa1.z + bf2f((unsigned short)xv[7])*wa1.w;
            }
            p += __shfl_xor(p, 1);
            p += __shfl_xor(p, 2);
            if (qd == 0) outAgg[r0 + row] = p + bagg[0];
        }
        __syncthreads();
        // coalesced V^T writeout
        {
            const int f = tid >> 2, seg = tid & 3;
            const int b = r0 >> 12, l0 = r0 & (L_ - 1);
            const uint4 a0 = *(const uint4*)&Vt_lds[f*72 + seg*16];
            const uint4 a1 = *(const uint4*)&Vt_lds[f*72 + seg*16 + 8];
            unsigned short* dst = outVt + ((size_t)(b*F_ + f))*L_ + l0 + seg*16;
            *(uint4*)dst = a0;
            *(uint4*)(dst + 8) = a1;
        }
    }
}

// Fused projections: blocks 0..511 leaf, 512..639 target(q), 640..703 node.
__global__ __launch_bounds__(256, 2)
void proj_all(const float* __restrict__ target, const float* __restrict__ node,
              const float* __restrict__ leaf,
              const unsigned short* __restrict__ Wq_t,
              const unsigned short* __restrict__ Wkv_t,
              const float* __restrict__ bq_s, const float* __restrict__ bkv,
              const float* __restrict__ Wagg, const float* __restrict__ bagg,
              unsigned short* __restrict__ q_bf, unsigned short* __restrict__ nk_bf,
              float* __restrict__ node_v, unsigned short* __restrict__ lk_bf,
              unsigned short* __restrict__ lvt, float* __restrict__ agg)
{
    __shared__ unsigned short Xs[64 * XSTR];      // 65 KB
    __shared__ unsigned short Vt_lds[64 * 72];    // 9 KB
    const int blk = blockIdx.x;
    if (blk < 512) {
        proj_body<2>(blk*64, Xs, Vt_lds, leaf, Wkv_t, bkv, Wagg, bagg,
                     lk_bf, nullptr, lvt, agg);
    } else if (blk < 640) {
        proj_body<0>((blk-512)*64, Xs, Vt_lds, target, Wq_t, bq_s, nullptr, nullptr,
                     q_bf, nullptr, nullptr, nullptr);
    } else {
        proj_body<1>((blk-640)*64, Xs, Vt_lds, node, Wkv_t, bkv, nullptr, nullptr,
                     nk_bf, node_v, nullptr, nullptr);
    }
}

// ---------------------------------------------------------------------------
// Fused suffix-scan + node_hat. One wave per (b,f); lane owns 8 node groups.
// Computes group sums G, cross-lane suffix scan, then node_hat directly
// (everything needed is already lane-local). Writes nh_t [B][F][N] bf16.
// ---------------------------------------------------------------------------
__global__ __launch_bounds__(256)
void scan_nh_kernel(const unsigned short* __restrict__ lvt,
                    const float* __restrict__ node_v,
                    const float* __restrict__ root,
                    const float* __restrict__ agg,
                    unsigned short* __restrict__ nh_t)
{
    const int gtid = blockIdx.x * 256 + threadIdx.x;
    const int wv   = gtid >> 6;
    const int lane = threadIdx.x & 63;
    const int b = wv >> 6;
    const int f = wv & 63;

    const unsigned short* vt = lvt + ((size_t)(b*F_ + f))*L_ + lane*64;
    const float rootf = root[b*F_ + f];
    short8 xv[8]; float nv[8]; float gv[8];
    #pragma unroll
    for (int g = 0; g < 8; ++g) {
        xv[g] = *(const short8*)(vt + g*8);
        nv[g] = node_v[((size_t)(b*N_ + lane*8 + g))*F_ + f];
        float s8 = 0.f;
        #pragma unroll
        for (int j = 0; j < 8; ++j) s8 += bf2f((unsigned short)xv[g][j]);
        gv[g] = (s8 + 8.f*(rootf + nv[g])) * (1.f/3.f);
    }

    float s[9];
    s[8] = 0.f;
    #pragma unroll
    for (int j = 7; j >= 0; --j) s[j] = s[j+1] + gv[j];

    float x = s[0];
    const float lsum = x;
    #pragma unroll
    for (int off = 1; off < 64; off <<= 1) {
        float t = __shfl_down(x, off);
        if (lane + off < 64) x += t;
    }
    const float excl = x - lsum;   // suffix sum over lanes > lane

    // node_hat for the 8 owned nodes
    const float* aggb = agg + (size_t)b*L_ + lane*64;
    unsigned short out8[8];
    #pragma unroll
    for (int g = 0; g < 8; ++g) {
        const float4 a0 = *(const float4*)(aggb + g*8);
        const float4 a1 = *(const float4*)(aggb + g*8 + 4);
        const float av[8] = {a0.x,a0.y,a0.z,a0.w, a1.x,a1.y,a1.z,a1.w};
        float mx = av[0];
        #pragma unroll
        for (int cc = 1; cc < 8; ++cc) mx = fmaxf(mx, av[cc]);
        float wgt[8]; float wsum = 0.f;
        #pragma unroll
        for (int cc = 0; cc < 8; ++cc) { wgt[cc] = __expf(av[cc] - mx); wsum += wgt[cc]; }

        const float tn = excl + s[g+1];
        float run = 0.f, acc = 0.f;
        #pragma unroll
        for (int cc = 7; cc >= 0; --cc) {
            const int ll = lane*64 + g*8 + cc;
            const float interp = (rootf + nv[g] + bf2f((unsigned short)xv[g][cc])) * (1.f/3.f);
            run += interp;
            const float up = (tn + run) / (float)(L_ - ll);
            acc = fmaf(wgt[cc], up, acc);
        }
        out8[g] = f2bf(acc / wsum);
    }
    *(uint4*)&nh_t[((size_t)(b*F_ + f))*N_ + lane*8] = *(const uint4*)out8;
}

// ---------------------------------------------------------------------------
// MFMA dual-softmax attention (round-4 verified per-wave math).
// ROUND 8: SLICES=8, grid 512 x 8 waves -> 2 blocks/CU = 16 waves/CU.
// pacc stored bf16 to keep combine traffic flat.
// ---------------------------------------------------------------------------
__global__ __launch_bounds__(512, 4)
void attn_kernel(const unsigned short* __restrict__ qb,
                 const unsigned short* __restrict__ nk,
                 const unsigned short* __restrict__ nht,
                 const unsigned short* __restrict__ lk,
                 const unsigned short* __restrict__ lvt,
                 unsigned short* __restrict__ pacc, float* __restrict__ pd)
{
    __shared__ unsigned short Ks[2][64*KSTR];   // 18 KB
    __shared__ unsigned short Vt[2][64*KSTR];   // 18 KB

    // 512 blocks; 64 consecutive wgs per XCD = exactly one batch per XCD.
    const int wg  = (blockIdx.x & 7) * 64 + (blockIdx.x >> 3);
    const int b   = wg >> 6;
    const int sl  = (wg >> 3) & 7;
    const int t0  = (wg & 7) * 128;

    const int tid = threadIdx.x;
    const int w   = tid >> 6;      // wave 0..7, owns t rows t0+16w..+15
    const int l   = tid & 63;
    const int c   = l & 15;
    const int h   = l >> 4;
    const int sm  = tid >> 3;      // staging row 0..63
    const int sc  = tid & 7;       // staging 16B chunk

    const unsigned short* qrow = qb + ((size_t)(b*T_ + t0 + w*16 + c))*F_ + 8*h;
    const short8 qf0 = *(const short8*)qrow;
    const short8 qf1 = *(const short8*)(qrow + 32);

    f32x4 accN[4] = {{0,0,0,0},{0,0,0,0},{0,0,0,0},{0,0,0,0}};
    f32x4 accL[4] = {{0,0,0,0},{0,0,0,0},{0,0,0,0},{0,0,0,0}};
    float dsN = 0.f, dsL = 0.f;

    const unsigned short* Knb = nk  + (size_t)b*N_*F_;
    const unsigned short* Klb = lk  + (size_t)b*L_*F_;
    const unsigned short* Vnb = nht + (size_t)b*F_*N_;   // [F][N]
    const unsigned short* Vlb = lvt + (size_t)b*F_*L_;   // [F][L]

    const int ti0 = sl * TPS;

    uint4 sk0, sv0;
    auto load_tile = [&](int ti) {
        if (ti < 8) {
            sk0 = *(const uint4*)(Knb + (size_t)ti*64*F_ + sm*64 + sc*8);
            sv0 = *(const uint4*)(Vnb + (size_t)sm*N_ + ti*64 + sc*8);
        } else {
            sk0 = *(const uint4*)(Klb + (size_t)(ti-8)*64*F_ + sm*64 + sc*8);
            sv0 = *(const uint4*)(Vlb + (size_t)sm*L_ + (ti-8)*64 + sc*8);
        }
    };
    auto write_tile = [&](int pb) {
        *(uint4*)&Ks[pb][sm*KSTR + sc*8] = sk0;
        *(uint4*)&Vt[pb][sm*KSTR + sc*8] = sv0;
    };

    load_tile(ti0);
    write_tile(0);
    __syncthreads();

    const int srcA = c + 16*((2*h) & 3);
    const int srcB = c + 16*((2*h + 1) & 3);
    const int hs   = h >> 1;

    for (int i = 0; i < TPS; ++i) {
        const int  ti  = ti0 + i;
        const bool isN = ti < 8;
        const int  pb  = i & 1;
        const bool nxt = (i + 1 < TPS);
        if (nxt) load_tile(ti + 1);

        f32x4 st[4] = {{0,0,0,0},{0,0,0,0},{0,0,0,0},{0,0,0,0}};
        #pragma unroll
        for (int ss = 0; ss < 4; ++ss) {
            const short8 kf0 = *(const short8*)&Ks[pb][(16*ss + c)*KSTR + 8*h];
            st[ss] = __builtin_amdgcn_mfma_f32_16x16x32_bf16(kf0, qf0, st[ss], 0,0,0);
            const short8 kf1 = *(const short8*)&Ks[pb][(16*ss + c)*KSTR + 32 + 8*h];
            st[ss] = __builtin_amdgcn_mfma_f32_16x16x32_bf16(kf1, qf1, st[ss], 0,0,0);
        }

        unsigned pk0[4], pk1[4];
        float psum = 0.f;
        #pragma unroll
        for (int ss = 0; ss < 4; ++ss) {
            #pragma unroll
            for (int r = 0; r < 4; ++r) { st[ss][r] = __expf(st[ss][r]); psum += st[ss][r]; }
            pk0[ss] = pack_bf(st[ss][0], st[ss][1]);
            pk1[ss] = pack_bf(st[ss][2], st[ss][3]);
        }
        if (isN) dsN += psum; else dsL += psum;

        #pragma unroll
        for (int k00 = 0; k00 < 2; ++k00) {
            const unsigned d0a = __shfl(pk0[2*k00+0], srcA);
            const unsigned d0b = __shfl(pk0[2*k00+1], srcA);
            const unsigned d1a = __shfl(pk1[2*k00+0], srcA);
            const unsigned d1b = __shfl(pk1[2*k00+1], srcA);
            const unsigned d2a = __shfl(pk0[2*k00+0], srcB);
            const unsigned d2b = __shfl(pk0[2*k00+1], srcB);
            const unsigned d3a = __shfl(pk1[2*k00+0], srcB);
            const unsigned d3b = __shfl(pk1[2*k00+1], srcB);
            const short8 bp = frag_from4(hs ? d0b : d0a, hs ? d1b : d1a,
                                         hs ? d2b : d2a, hs ? d3b : d3a);
            if (isN) {
                #pragma unroll
                for (int s2 = 0; s2 < 4; ++s2) {
                    const short8 af = *(const short8*)&Vt[pb][(16*s2 + c)*KSTR + 32*k00 + 8*h];
                    accN[s2] = __builtin_amdgcn_mfma_f32_16x16x32_bf16(af, bp, accN[s2], 0,0,0);
                }
            } else {
                #pragma unroll
                for (int s2 = 0; s2 < 4; ++s2) {
                    const short8 af = *(const short8*)&Vt[pb][(16*s2 + c)*KSTR + 32*k00 + 8*h];
                    accL[s2] = __builtin_amdgcn_mfma_f32_16x16x32_bf16(af, bp, accL[s2], 0,0,0);
                }
            }
        }

        if (nxt) {
            write_tile(pb ^ 1);
            __syncthreads();
        }
    }

    dsN += __shfl_xor(dsN, 16);  dsN += __shfl_xor(dsN, 32);
    dsL += __shfl_xor(dsL, 16);  dsL += __shfl_xor(dsL, 32);

    // bf16 partial store: lane owns t'=c, f = 16*s2+4h+r
    const int gt = b*T_ + t0 + w*16 + c;
    unsigned short* baseN = pacc + (((size_t)sl*(B_*T_) + gt)*2 + 0)*F_;
    unsigned short* baseL = baseN + F_;
    #pragma unroll
    for (int s2 = 0; s2 < 4; ++s2) {
        *(unsigned*)&baseN[s2*16 + 4*h]     = pack_bf(accN[s2][0], accN[s2][1]);
        *(unsigned*)&baseN[s2*16 + 4*h + 2] = pack_bf(accN[s2][2], accN[s2][3]);
        *(unsigned*)&baseL[s2*16 + 4*h]     = pack_bf(accL[s2][0], accL[s2][1]);
        *(unsigned*)&baseL[s2*16 + 4*h + 2] = pack_bf(accL[s2][2], accL[s2][3]);
    }
    if (h == 0) {
        pd[((size_t)sl*(B_*T_) + gt)*2 + 0] = dsN;
        pd[((size_t)sl*(B_*T_) + gt)*2 + 1] = dsL;
    }
}

// ---------------------------------------------------------------------------
// Combine slices + final feature softmax. One wave per target, lane = f.
// ---------------------------------------------------------------------------
__global__ __launch_bounds__(256)
void combine_kernel(const unsigned short* __restrict__ pacc,
                    const float* __restrict__ pd,
                    float* __restrict__ out)
{
    const int gt = (blockIdx.x * 256 + threadIdx.x) >> 6;
    const int f  = threadIdx.x & 63;

    float aN = 0.f, aL = 0.f, dN = 0.f, dL = 0.f;
    #pragma unroll
    for (int s = 0; s < SLICES; ++s) {
        const size_t base = ((size_t)s*(B_*T_) + gt)*2;
        aN += bf2f(pacc[(base + 0)*F_ + f]);
        aL += bf2f(pacc[(base + 1)*F_ + f]);
        dN += pd[base + 0];
        dL += pd[base + 1];
    }
    float lg = aN / dN + aL / dL;
    float mx = lg;
    #pragma unroll
    for (int off = 1; off < 64; off <<= 1) mx = fmaxf(mx, __shfl_xor(mx, off));
    const float e = __expf(lg - mx);
    float ssum = e;
    #pragma unroll
    for (int off = 1; off < 64; off <<= 1) ssum += __shfl_xor(ssum, off);
    out[(size_t)gt*F_ + f] = e / ssum;
}

// ---------------------------------------------------------------------------
extern "C" void kernel_launch(void* const* d_in, const int* in_sizes, int n_in,
                              void* d_out, int out_size, void* d_ws, size_t ws_size,
                              hipStream_t stream)
{
    const float* root   = (const float*)d_in[0];
    const float* node   = (const float*)d_in[1];
    const float* leaf   = (const float*)d_in[2];
    const float* target = (const float*)d_in[3];
    const float* Wq   = (const float*)d_in[4];
    const float* bq   = (const float*)d_in[5];
    const float* Wk   = (const float*)d_in[6];
    const float* bk   = (const float*)d_in[7];
    const float* Wv   = (const float*)d_in[8];
    const float* bv   = (const float*)d_in[9];
    const float* Wagg = (const float*)d_in[10];
    const float* bagg = (const float*)d_in[11];
    float* out = (float*)d_out;

    // workspace layout (bytes), ~29 MB
    char* wp = (char*)d_ws;
    unsigned short* q_bf  = (unsigned short*)wp; wp += (size_t)B_*T_*F_*2;       // 1 MB
    unsigned short* nk_bf = (unsigned short*)wp; wp += (size_t)B_*N_*F_*2;       // 0.5 MB
    unsigned short* lk_bf = (unsigned short*)wp; wp += (size_t)B_*L_*F_*2;       // 4 MB
    unsigned short* lvt   = (unsigned short*)wp; wp += (size_t)B_*F_*L_*2;       // 4 MB
    unsigned short* nht   = (unsigned short*)wp; wp += (size_t)B_*F_*N_*2;       // 0.5 MB
    unsigned short* Wq_t  = (unsigned short*)wp; wp += (size_t)64*D_*2;          // 64 KB
    unsigned short* Wkv_t = (unsigned short*)wp; wp += (size_t)128*D_*2;         // 128 KB
    float* node_v = (float*)wp; wp += (size_t)B_*N_*F_*4;                        // 1 MB
    float* agg    = (float*)wp; wp += (size_t)B_*L_*4;                           // 128 KB
    float* bq_s   = (float*)wp; wp += 512;
    float* bkv    = (float*)wp; wp += 512;
    unsigned short* pacc = (unsigned short*)wp; wp += (size_t)SLICES*B_*T_*2*F_*2; // 16.8 MB
    float* pd     = (float*)wp;                                                  // 512 KB

    prep_kernel<<<193, 64, 0, stream>>>(Wq, bq, Wk, bk, Wv, bv, Wq_t, Wkv_t, bq_s, bkv);
    proj_all<<<704, 256, 0, stream>>>(target, node, leaf, Wq_t, Wkv_t, bq_s, bkv,
                                      Wagg, bagg, q_bf, nk_bf, node_v, lk_bf, lvt, agg);
    scan_nh_kernel<<<128, 256, 0, stream>>>(lvt, node_v, root, agg, nht);
    attn_kernel<<<B_*(T_/128)*SLICES, 512, 0, stream>>>(q_bf, nk_bf, nht, lk_bf, lvt, pacc, pd);
    combine_kernel<<<(B_*T_)/4, 256, 0, stream>>>(pacc, pd, out);
}

// Round 9
// 80.653 us; speedup vs baseline: 8.7772x; 1.0034x over previous
//
#include <hip/hip_runtime.h>

// DecoderAttention: B=8, T=1024, N=512, L=4096, D=512, F=64, BR=8
#define B_ 8
#define T_ 1024
#define N_ 512
#define L_ 4096
#define D_ 512
#define F_ 64
#define SLICES 8
#define TPS 9     // tiles per slice (72 total: 8 node + 64 leaf)
#define KSTR 72   // attn LDS row stride (bf16) for K / V^T tiles
#define XSTR 520  // proj LDS row stride (bf16)

typedef __attribute__((ext_vector_type(8))) short short8;
typedef __attribute__((ext_vector_type(4))) float f32x4;

__device__ __forceinline__ unsigned short f2bf(float x){
    unsigned u = __builtin_bit_cast(unsigned, x);
    u += 0x7FFFu + ((u >> 16) & 1u);           // RNE
    return (unsigned short)(u >> 16);
}
__device__ __forceinline__ unsigned pack_bf(float lo, float hi){
    return (unsigned)f2bf(lo) | ((unsigned)f2bf(hi) << 16);
}
__device__ __forceinline__ float bf2f(unsigned short s){
    return __builtin_bit_cast(float, ((unsigned)s) << 16);
}
__device__ __forceinline__ short8 frag_from4(unsigned d0, unsigned d1, unsigned d2, unsigned d3){
    union { unsigned u[4]; short8 s; } t;
    t.u[0] = d0; t.u[1] = d1; t.u[2] = d2; t.u[3] = d3;
    return t.s;
}

// ---------------------------------------------------------------------------
// Weight prep: transposed bf16 weights + bias vectors.
// ---------------------------------------------------------------------------
__global__ __launch_bounds__(64)
void prep_kernel(const float* __restrict__ Wq, const float* __restrict__ bq,
                 const float* __restrict__ Wk, const float* __restrict__ bk,
                 const float* __restrict__ Wv, const float* __restrict__ bv,
                 unsigned short* __restrict__ Wq_t, unsigned short* __restrict__ Wkv_t,
                 float* __restrict__ bq_s, float* __restrict__ bkv)
{
    const int n = blockIdx.x;
    const int lane = threadIdx.x;
    if (n == 192) {
        bq_s[lane]   = bq[lane] * 0.125f;
        bkv[lane]    = bk[lane];
        bkv[64+lane] = bv[lane];
        return;
    }
    const int d0 = lane * 8;
    unsigned short t[8];
    if (n < 64) {
        #pragma unroll
        for (int j = 0; j < 8; ++j) t[j] = f2bf(Wq[(size_t)(d0+j)*F_ + n] * 0.125f);
        *(uint4*)&Wq_t[(size_t)n*D_ + d0] = make_uint4(
            (unsigned)t[0]|((unsigned)t[1]<<16), (unsigned)t[2]|((unsigned)t[3]<<16),
            (unsigned)t[4]|((unsigned)t[5]<<16), (unsigned)t[6]|((unsigned)t[7]<<16));
    } else {
        const int nn  = n - 64;
        const float* W = (nn < 64) ? Wk : Wv;
        const int col = nn & 63;
        #pragma unroll
        for (int j = 0; j < 8; ++j) t[j] = f2bf(W[(size_t)(d0+j)*F_ + col]);
        *(uint4*)&Wkv_t[(size_t)nn*D_ + d0] = make_uint4(
            (unsigned)t[0]|((unsigned)t[1]<<16), (unsigned)t[2]|((unsigned)t[3]<<16),
            (unsigned)t[4]|((unsigned)t[5]<<16), (unsigned)t[6]|((unsigned)t[7]<<16));
    }
}

// ---------------------------------------------------------------------------
// Projection GEMM body (verified round 6), as a device function so one fused
// kernel dispatches leaf/target/node blocks. Weights-in-registers.
// ---------------------------------------------------------------------------
template<int MODE>
__device__ __forceinline__ void proj_body(
    int r0, unsigned short* Xs, unsigned short* Vt_lds,
    const float* __restrict__ X,
    const unsigned short* __restrict__ Wt,
    const float* __restrict__ bias,
    const float* __restrict__ Wagg, const float* __restrict__ bagg,
    unsigned short* __restrict__ outK, float* __restrict__ outVf,
    unsigned short* __restrict__ outVt, float* __restrict__ outAgg)
{
    constexpr int NPW = (MODE == 0) ? 1 : 2;
    const int tid = threadIdx.x;
    const int w = tid >> 6, l = tid & 63, c = l & 15, h = l >> 4;

    // B-frag preload (latency hides under staging)
    short8 breg[NPW][16];
    #pragma unroll
    for (int p = 0; p < NPW; ++p) {
        const unsigned short* wrow = Wt + (size_t)(16*(NPW*w + p) + c)*D_ + 8*h;
        #pragma unroll
        for (int kk = 0; kk < 16; ++kk)
            breg[p][kk] = *(const short8*)(wrow + kk*32);
    }

    // stage 64x512 f32 -> bf16 LDS
    const float4* xsrc = (const float4*)(X + (size_t)r0 * D_);
    #pragma unroll 4
    for (int j = 0; j < 32; ++j) {
        const int s = tid + j * 256;
        const float4 v = xsrc[s];
        *(uint2*)&Xs[(s >> 7)*XSTR + (s & 127)*4] =
            make_uint2(pack_bf(v.x, v.y), pack_bf(v.z, v.w));
    }
    __syncthreads();

    f32x4 acc[NPW][4];
    #pragma unroll
    for (int p = 0; p < NPW; ++p)
        #pragma unroll
        for (int m = 0; m < 4; ++m) acc[p][m] = (f32x4){0,0,0,0};

    #pragma unroll
    for (int kk = 0; kk < 16; ++kk) {
        #pragma unroll
        for (int m = 0; m < 4; ++m) {
            const short8 af = *(const short8*)&Xs[(16*m + c)*XSTR + kk*32 + 8*h];
            #pragma unroll
            for (int p = 0; p < NPW; ++p)
                acc[p][m] = __builtin_amdgcn_mfma_f32_16x16x32_bf16(af, breg[p][kk], acc[p][m], 0,0,0);
        }
    }

    #pragma unroll
    for (int p = 0; p < NPW; ++p) {
        const int s2g = NPW*w + p;
        const float bc = bias[16*s2g + c];
        if (MODE == 0 || s2g < 4) {
            #pragma unroll
            for (int m = 0; m < 4; ++m)
                #pragma unroll
                for (int r = 0; r < 4; ++r)
                    outK[(size_t)(r0 + 16*m + 4*h + r)*F_ + 16*s2g + c] = f2bf(acc[p][m][r] + bc);
        } else if (MODE == 1) {
            #pragma unroll
            for (int m = 0; m < 4; ++m)
                #pragma unroll
                for (int r = 0; r < 4; ++r)
                    outVf[(size_t)(r0 + 16*m + 4*h + r)*F_ + 16*(s2g-4) + c] = acc[p][m][r] + bc;
        } else {
            #pragma unroll
            for (int m = 0; m < 4; ++m)
                #pragma unroll
                for (int r = 0; r < 4; ++r)
                    Vt_lds[(16*(s2g-4) + c)*72 + 16*m + 4*h + r] = f2bf(acc[p][m][r] + bc);
        }
    }

    if constexpr (MODE == 2) {
        // agg logit per leaf row from bf16 Xs
        {
            const int row = tid >> 2, qd = tid & 3;
            const unsigned short* xr = &Xs[row*XSTR + qd*128];
            const float* wr = Wagg + qd*128;
            float p = 0.f;
            #pragma unroll
            for (int j = 0; j < 16; ++j) {
                const short8 xv = *(const short8*)(xr + j*8);
                const float4 wa0 = *(const float4*)(wr + j*8);
                const float4 wa1 = *(const float4*)(wr + j*8 + 4);
                p += bf2f((unsigned short)xv[0])*wa0.x + bf2f((unsigned short)xv[1])*wa0.y
                   + bf2f((unsigned short)xv[2])*wa0.z + bf2f((unsigned short)xv[3])*wa0.w
                   + bf2f((unsigned short)xv[4])*wa1.x + bf2f((unsigned short)xv[5])*wa1.y
                   + bf2f((unsigned short)xv[6])*wa1.z + bf2f((unsigned short)xv[7])*wa1.w;
            }
            p += __shfl_xor(p, 1);
            p += __shfl_xor(p, 2);
            if (qd == 0) outAgg[r0 + row] = p + bagg[0];
        }
        __syncthreads();
        // coalesced V^T writeout
        {
            const int f = tid >> 2, seg = tid & 3;
            const int b = r0 >> 12, l0 = r0 & (L_ - 1);
            const uint4 a0 = *(const uint4*)&Vt_lds[f*72 + seg*16];
            const uint4 a1 = *(const uint4*)&Vt_lds[f*72 + seg*16 + 8];
            unsigned short* dst = outVt + ((size_t)(b*F_ + f))*L_ + l0 + seg*16;
            *(uint4*)dst = a0;
            *(uint4*)(dst + 8) = a1;
        }
    }
}

// Fused projections: blocks 0..511 leaf, 512..639 target(q), 640..703 node.
__global__ __launch_bounds__(256, 2)
void proj_all(const float* __restrict__ target, const float* __restrict__ node,
              const float* __restrict__ leaf,
              const unsigned short* __restrict__ Wq_t,
              const unsigned short* __restrict__ Wkv_t,
              const float* __restrict__ bq_s, const float* __restrict__ bkv,
              const float* __restrict__ Wagg, const float* __restrict__ bagg,
              unsigned short* __restrict__ q_bf, unsigned short* __restrict__ nk_bf,
              float* __restrict__ node_v, unsigned short* __restrict__ lk_bf,
              unsigned short* __restrict__ lvt, float* __restrict__ agg)
{
    __shared__ unsigned short Xs[64 * XSTR];      // 65 KB
    __shared__ unsigned short Vt_lds[64 * 72];    // 9 KB
    const int blk = blockIdx.x;
    if (blk < 512) {
        proj_body<2>(blk*64, Xs, Vt_lds, leaf, Wkv_t, bkv, Wagg, bagg,
                     lk_bf, nullptr, lvt, agg);
    } else if (blk < 640) {
        proj_body<0>((blk-512)*64, Xs, Vt_lds, target, Wq_t, bq_s, nullptr, nullptr,
                     q_bf, nullptr, nullptr, nullptr);
    } else {
        proj_body<1>((blk-640)*64, Xs, Vt_lds, node, Wkv_t, bkv, nullptr, nullptr,
                     nk_bf, node_v, nullptr, nullptr);
    }
}

// ---------------------------------------------------------------------------
// Fused suffix-scan + node_hat. One wave per (b,f); lane owns 8 node groups.
// Computes group sums G, cross-lane suffix scan, then node_hat directly
// (everything needed is already lane-local). Writes nh_t [B][F][N] bf16.
// ---------------------------------------------------------------------------
__global__ __launch_bounds__(256)
void scan_nh_kernel(const unsigned short* __restrict__ lvt,
                    const float* __restrict__ node_v,
                    const float* __restrict__ root,
                    const float* __restrict__ agg,
                    unsigned short* __restrict__ nh_t)
{
    const int gtid = blockIdx.x * 256 + threadIdx.x;
    const int wv   = gtid >> 6;
    const int lane = threadIdx.x & 63;
    const int b = wv >> 6;
    const int f = wv & 63;

    const unsigned short* vt = lvt + ((size_t)(b*F_ + f))*L_ + lane*64;
    const float rootf = root[b*F_ + f];
    short8 xv[8]; float nv[8]; float gv[8];
    #pragma unroll
    for (int g = 0; g < 8; ++g) {
        xv[g] = *(const short8*)(vt + g*8);
        nv[g] = node_v[((size_t)(b*N_ + lane*8 + g))*F_ + f];
        float s8 = 0.f;
        #pragma unroll
        for (int j = 0; j < 8; ++j) s8 += bf2f((unsigned short)xv[g][j]);
        gv[g] = (s8 + 8.f*(rootf + nv[g])) * (1.f/3.f);
    }

    float s[9];
    s[8] = 0.f;
    #pragma unroll
    for (int j = 7; j >= 0; --j) s[j] = s[j+1] + gv[j];

    float x = s[0];
    const float lsum = x;
    #pragma unroll
    for (int off = 1; off < 64; off <<= 1) {
        float t = __shfl_down(x, off);
        if (lane + off < 64) x += t;
    }
    const float excl = x - lsum;   // suffix sum over lanes > lane

    // node_hat for the 8 owned nodes
    const float* aggb = agg + (size_t)b*L_ + lane*64;
    unsigned short out8[8];
    #pragma unroll
    for (int g = 0; g < 8; ++g) {
        const float4 a0 = *(const float4*)(aggb + g*8);
        const float4 a1 = *(const float4*)(aggb + g*8 + 4);
        const float av[8] = {a0.x,a0.y,a0.z,a0.w, a1.x,a1.y,a1.z,a1.w};
        float mx = av[0];
        #pragma unroll
        for (int cc = 1; cc < 8; ++cc) mx = fmaxf(mx, av[cc]);
        float wgt[8]; float wsum = 0.f;
        #pragma unroll
        for (int cc = 0; cc < 8; ++cc) { wgt[cc] = __expf(av[cc] - mx); wsum += wgt[cc]; }

        const float tn = excl + s[g+1];
        float run = 0.f, acc = 0.f;
        #pragma unroll
        for (int cc = 7; cc >= 0; --cc) {
            const int ll = lane*64 + g*8 + cc;
            const float interp = (rootf + nv[g] + bf2f((unsigned short)xv[g][cc])) * (1.f/3.f);
            run += interp;
            const float up = (tn + run) / (float)(L_ - ll);
            acc = fmaf(wgt[cc], up, acc);
        }
        out8[g] = f2bf(acc / wsum);
    }
    *(uint4*)&nh_t[((size_t)(b*F_ + f))*N_ + lane*8] = *(const uint4*)out8;
}

// ---------------------------------------------------------------------------
// MFMA dual-softmax attention (round-4 verified per-wave math).
// ROUND 8: SLICES=8, grid 512 x 8 waves -> 2 blocks/CU = 16 waves/CU.
// pacc stored bf16 to keep combine traffic flat.
// ---------------------------------------------------------------------------
__global__ __launch_bounds__(512, 4)
void attn_kernel(const unsigned short* __restrict__ qb,
                 const unsigned short* __restrict__ nk,
                 const unsigned short* __restrict__ nht,
                 const unsigned short* __restrict__ lk,
                 const unsigned short* __restrict__ lvt,
                 unsigned short* __restrict__ pacc, float* __restrict__ pd)
{
    __shared__ unsigned short Ks[2][64*KSTR];   // 18 KB
    __shared__ unsigned short Vt[2][64*KSTR];   // 18 KB

    // 512 blocks; 64 consecutive wgs per XCD = exactly one batch per XCD.
    const int wg  = (blockIdx.x & 7) * 64 + (blockIdx.x >> 3);
    const int b   = wg >> 6;
    const int sl  = (wg >> 3) & 7;
    const int t0  = (wg & 7) * 128;

    const int tid = threadIdx.x;
    const int w   = tid >> 6;      // wave 0..7, owns t rows t0+16w..+15
    const int l   = tid & 63;
    const int c   = l & 15;
    const int h   = l >> 4;
    const int sm  = tid >> 3;      // staging row 0..63
    const int sc  = tid & 7;       // staging 16B chunk

    const unsigned short* qrow = qb + ((size_t)(b*T_ + t0 + w*16 + c))*F_ + 8*h;
    const short8 qf0 = *(const short8*)qrow;
    const short8 qf1 = *(const short8*)(qrow + 32);

    f32x4 accN[4] = {{0,0,0,0},{0,0,0,0},{0,0,0,0},{0,0,0,0}};
    f32x4 accL[4] = {{0,0,0,0},{0,0,0,0},{0,0,0,0},{0,0,0,0}};
    float dsN = 0.f, dsL = 0.f;

    const unsigned short* Knb = nk  + (size_t)b*N_*F_;
    const unsigned short* Klb = lk  + (size_t)b*L_*F_;
    const unsigned short* Vnb = nht + (size_t)b*F_*N_;   // [F][N]
    const unsigned short* Vlb = lvt + (size_t)b*F_*L_;   // [F][L]

    const int ti0 = sl * TPS;

    uint4 sk0, sv0;
    auto load_tile = [&](int ti) {
        if (ti < 8) {
            sk0 = *(const uint4*)(Knb + (size_t)ti*64*F_ + sm*64 + sc*8);
            sv0 = *(const uint4*)(Vnb + (size_t)sm*N_ + ti*64 + sc*8);
        } else {
            sk0 = *(const uint4*)(Klb + (size_t)(ti-8)*64*F_ + sm*64 + sc*8);
            sv0 = *(const uint4*)(Vlb + (size_t)sm*L_ + (ti-8)*64 + sc*8);
        }
    };
    auto write_tile = [&](int pb) {
        *(uint4*)&Ks[pb][sm*KSTR + sc*8] = sk0;
        *(uint4*)&Vt[pb][sm*KSTR + sc*8] = sv0;
    };

    load_tile(ti0);
    write_tile(0);
    __syncthreads();

    const int srcA = c + 16*((2*h) & 3);
    const int srcB = c + 16*((2*h + 1) & 3);
    const int hs   = h >> 1;

    for (int i = 0; i < TPS; ++i) {
        const int  ti  = ti0 + i;
        const bool isN = ti < 8;
        const int  pb  = i & 1;
        const bool nxt = (i + 1 < TPS);
        if (nxt) load_tile(ti + 1);

        f32x4 st[4] = {{0,0,0,0},{0,0,0,0},{0,0,0,0},{0,0,0,0}};
        #pragma unroll
        for (int ss = 0; ss < 4; ++ss) {
            const short8 kf0 = *(const short8*)&Ks[pb][(16*ss + c)*KSTR + 8*h];
            st[ss] = __builtin_amdgcn_mfma_f32_16x16x32_bf16(kf0, qf0, st[ss], 0,0,0);
            const short8 kf1 = *(const short8*)&Ks[pb][(16*ss + c)*KSTR + 32 + 8*h];
            st[ss] = __builtin_amdgcn_mfma_f32_16x16x32_bf16(kf1, qf1, st[ss], 0,0,0);
        }

        unsigned pk0[4], pk1[4];
        float psum = 0.f;
        #pragma unroll
        for (int ss = 0; ss < 4; ++ss) {
            #pragma unroll
            for (int r = 0; r < 4; ++r) { st[ss][r] = __expf(st[ss][r]); psum += st[ss][r]; }
            pk0[ss] = pack_bf(st[ss][0], st[ss][1]);
            pk1[ss] = pack_bf(st[ss][2], st[ss][3]);
        }
        if (isN) dsN += psum; else dsL += psum;

        #pragma unroll
        for (int k00 = 0; k00 < 2; ++k00) {
            const unsigned d0a = __shfl(pk0[2*k00+0], srcA);
            const unsigned d0b = __shfl(pk0[2*k00+1], srcA);
            const unsigned d1a = __shfl(pk1[2*k00+0], srcA);
            const unsigned d1b = __shfl(pk1[2*k00+1], srcA);
            const unsigned d2a = __shfl(pk0[2*k00+0], srcB);
            const unsigned d2b = __shfl(pk0[2*k00+1], srcB);
            const unsigned d3a = __shfl(pk1[2*k00+0], srcB);
            const unsigned d3b = __shfl(pk1[2*k00+1], srcB);
            const short8 bp = frag_from4(hs ? d0b : d0a, hs ? d1b : d1a,
                                         hs ? d2b : d2a, hs ? d3b : d3a);
            if (isN) {
                #pragma unroll
                for (int s2 = 0; s2 < 4; ++s2) {
                    const short8 af = *(const short8*)&Vt[pb][(16*s2 + c)*KSTR + 32*k00 + 8*h];
                    accN[s2] = __builtin_amdgcn_mfma_f32_16x16x32_bf16(af, bp, accN[s2], 0,0,0);
                }
            } else {
                #pragma unroll
                for (int s2 = 0; s2 < 4; ++s2) {
                    const short8 af = *(const short8*)&Vt[pb][(16*s2 + c)*KSTR + 32*k00 + 8*h];
                    accL[s2] = __builtin_amdgcn_mfma_f32_16x16x32_bf16(af, bp, accL[s2], 0,0,0);
                }
            }
        }

        if (nxt) {
            write_tile(pb ^ 1);
            __syncthreads();
        }
    }

    dsN += __shfl_xor(dsN, 16);  dsN += __shfl_xor(dsN, 32);
    dsL += __shfl_xor(dsL, 16);  dsL += __shfl_xor(dsL, 32);

    // bf16 partial store: lane owns t'=c, f = 16*s2+4h+r
    const int gt = b*T_ + t0 + w*16 + c;
    unsigned short* baseN = pacc + (((size_t)sl*(B_*T_) + gt)*2 + 0)*F_;
    unsigned short* baseL = baseN + F_;
    #pragma unroll
    for (int s2 = 0; s2 < 4; ++s2) {
        *(unsigned*)&baseN[s2*16 + 4*h]     = pack_bf(accN[s2][0], accN[s2][1]);
        *(unsigned*)&baseN[s2*16 + 4*h + 2] = pack_bf(accN[s2][2], accN[s2][3]);
        *(unsigned*)&baseL[s2*16 + 4*h]     = pack_bf(accL[s2][0], accL[s2][1]);
        *(unsigned*)&baseL[s2*16 + 4*h + 2] = pack_bf(accL[s2][2], accL[s2][3]);
    }
    if (h == 0) {
        pd[((size_t)sl*(B_*T_) + gt)*2 + 0] = dsN;
        pd[((size_t)sl*(B_*T_) + gt)*2 + 1] = dsL;
    }
}

// ---------------------------------------------------------------------------
// Combine slices + final feature softmax. One wave per target, lane = f.
// ---------------------------------------------------------------------------
__global__ __launch_bounds__(256)
void combine_kernel(const unsigned short* __restrict__ pacc,
                    const float* __restrict__ pd,
                    float* __restrict__ out)
{
    const int gt = (blockIdx.x * 256 + threadIdx.x) >> 6;
    const int f  = threadIdx.x & 63;

    float aN = 0.f, aL = 0.f, dN = 0.f, dL = 0.f;
    #pragma unroll
    for (int s = 0; s < SLICES; ++s) {
        const size_t base = ((size_t)s*(B_*T_) + gt)*2;
        aN += bf2f(pacc[(base + 0)*F_ + f]);
        aL += bf2f(pacc[(base + 1)*F_ + f]);
        dN += pd[base + 0];
        dL += pd[base + 1];
    }
    float lg = aN / dN + aL / dL;
    float mx = lg;
    #pragma unroll
    for (int off = 1; off < 64; off <<= 1) mx = fmaxf(mx, __shfl_xor(mx, off));
    const float e = __expf(lg - mx);
    float ssum = e;
    #pragma unroll
    for (int off = 1; off < 64; off <<= 1) ssum += __shfl_xor(ssum, off);
    out[(size_t)gt*F_ + f] = e / ssum;
}

// ---------------------------------------------------------------------------
extern "C" void kernel_launch(void* const* d_in, const int* in_sizes, int n_in,
                              void* d_out, int out_size, void* d_ws, size_t ws_size,
                              hipStream_t stream)
{
    const float* root   = (const float*)d_in[0];
    const float* node   = (const float*)d_in[1];
    const float* leaf   = (const float*)d_in[2];
    const float* target = (const float*)d_in[3];
    const float* Wq   = (const float*)d_in[4];
    const float* bq   = (const float*)d_in[5];
    const float* Wk   = (const float*)d_in[6];
    const float* bk   = (const float*)d_in[7];
    const float* Wv   = (const float*)d_in[8];
    const float* bv   = (const float*)d_in[9];
    const float* Wagg = (const float*)d_in[10];
    const float* bagg = (const float*)d_in[11];
    float* out = (float*)d_out;

    // workspace layout (bytes), ~29 MB
    char* wp = (char*)d_ws;
    unsigned short* q_bf  = (unsigned short*)wp; wp += (size_t)B_*T_*F_*2;       // 1 MB
    unsigned short* nk_bf = (unsigned short*)wp; wp += (size_t)B_*N_*F_*2;       // 0.5 MB
    unsigned short* lk_bf = (unsigned short*)wp; wp += (size_t)B_*L_*F_*2;       // 4 MB
    unsigned short* lvt   = (unsigned short*)wp; wp += (size_t)B_*F_*L_*2;       // 4 MB
    unsigned short* nht   = (unsigned short*)wp; wp += (size_t)B_*F_*N_*2;       // 0.5 MB
    unsigned short* Wq_t  = (unsigned short*)wp; wp += (size_t)64*D_*2;          // 64 KB
    unsigned short* Wkv_t = (unsigned short*)wp; wp += (size_t)128*D_*2;         // 128 KB
    float* node_v = (float*)wp; wp += (size_t)B_*N_*F_*4;                        // 1 MB
    float* agg    = (float*)wp; wp += (size_t)B_*L_*4;                           // 128 KB
    float* bq_s   = (float*)wp; wp += 512;
    float* bkv    = (float*)wp; wp += 512;
    unsigned short* pacc = (unsigned short*)wp; wp += (size_t)SLICES*B_*T_*2*F_*2; // 16.8 MB
    float* pd     = (float*)wp;                                                  // 512 KB

    prep_kernel<<<193, 64, 0, stream>>>(Wq, bq, Wk, bk, Wv, bv, Wq_t, Wkv_t, bq_s, bkv);
    proj_all<<<704, 256, 0, stream>>>(target, node, leaf, Wq_t, Wkv_t, bq_s, bkv,
                                      Wagg, bagg, q_bf, nk_bf, node_v, lk_bf, lvt, agg);
    scan_nh_kernel<<<128, 256, 0, stream>>>(lvt, node_v, root, agg, nht);
    attn_kernel<<<B_*(T_/128)*SLICES, 512, 0, stream>>>(q_bf, nk_bf, nht, lk_bf, lvt, pacc, pd);
    combine_kernel<<<(B_*T_)/4, 256, 0, stream>>>(pacc, pd, out);
}